// Round 1
// baseline (632.220 us; speedup 1.0000x reference)
//
#include <hip/hip_runtime.h>
#include <hip/hip_bf16.h>
#include <stdint.h>

typedef __attribute__((ext_vector_type(8))) short short8;
typedef __attribute__((ext_vector_type(4))) float f32x4;

#define DDIM 128

__device__ __forceinline__ unsigned short f2bf(float f) {
  union { float f; unsigned u; } v; v.f = f;
  unsigned u = v.u + 0x7FFFu + ((v.u >> 16) & 1u);  // round-to-nearest-even
  return (unsigned short)(u >> 16);
}
__device__ __forceinline__ float bf2f(unsigned short b) {
  union { unsigned u; float f; } v; v.u = ((unsigned)b) << 16;
  return v.f;
}

// ---- weights fp32 -> bf16 staging (64 KB total, L1/L2 resident afterwards)
__global__ void convW(const float* __restrict__ W1, const float* __restrict__ W2,
                      unsigned short* __restrict__ wb) {
  int i = blockIdx.x * blockDim.x + threadIdx.x;  // 32768 threads
  if (i < 16384)      wb[i] = f2bf(W1[i]);
  else if (i < 32768) wb[i] = f2bf(W2[i - 16384]);
}

// ---- fused projection: per 16-row tile compute y1 = x@W1^T, y2 = x@W2^T,
//      write Aout = bf16(y1+b1 + y2 + b2)  (src-side gather operand)
//            Qout = bf16(y2)               (dst-side gather operand)
//            Pout = y1+b1 (fp32)           (accumulator init = self-loop term)
__global__ __launch_bounds__(256) void proj(
    const float* __restrict__ x, int ntiles,
    const unsigned short* __restrict__ wb,   // [2][128*128] bf16
    const float* __restrict__ b1, const float* __restrict__ b2,
    unsigned short* __restrict__ Aout, unsigned short* __restrict__ Qout,
    float* __restrict__ Pout) {
  const int lane  = threadIdx.x & 63;
  const int wid   = threadIdx.x >> 6;
  const int col16 = lane & 15;
  const int kgrp  = lane >> 4;
  const int wavesTotal = gridDim.x * 4;

  for (int t = blockIdx.x * 4 + wid; t < ntiles; t += wavesTotal) {
    const int row = t * 16 + col16;
    f32x4 acc[2][8];
#pragma unroll
    for (int w = 0; w < 2; ++w)
#pragma unroll
      for (int ct = 0; ct < 8; ++ct)
        acc[w][ct] = (f32x4){0.f, 0.f, 0.f, 0.f};

#pragma unroll
    for (int ks = 0; ks < 4; ++ks) {
      const float* xp = x + (size_t)row * DDIM + ks * 32 + kgrp * 8;
      float4 xa = *(const float4*)xp;
      float4 xb = *(const float4*)(xp + 4);
      short8 a;
      a[0] = (short)f2bf(xa.x); a[1] = (short)f2bf(xa.y);
      a[2] = (short)f2bf(xa.z); a[3] = (short)f2bf(xa.w);
      a[4] = (short)f2bf(xb.x); a[5] = (short)f2bf(xb.y);
      a[6] = (short)f2bf(xb.z); a[7] = (short)f2bf(xb.w);
#pragma unroll
      for (int w = 0; w < 2; ++w) {
        const unsigned short* wp = wb + w * 16384;
#pragma unroll
        for (int ct = 0; ct < 8; ++ct) {
          short8 b = *(const short8*)(wp + (size_t)(ct * 16 + col16) * DDIM + ks * 32 + kgrp * 8);
          acc[w][ct] = __builtin_amdgcn_mfma_f32_16x16x32_bf16(a, b, acc[w][ct], 0, 0, 0);
        }
      }
    }

#pragma unroll
    for (int ct = 0; ct < 8; ++ct) {
      const int c = ct * 16 + col16;
      const float bb1 = b1[c], bb2 = b2[c];
#pragma unroll
      for (int i = 0; i < 4; ++i) {
        const int r = t * 16 + kgrp * 4 + i;
        const float y1 = acc[0][ct][i] + bb1;
        const float y2 = acc[1][ct][i];
        Pout[(size_t)r * DDIM + c] = y1;
        Aout[(size_t)r * DDIM + c] = f2bf(y1 + y2 + bb2);
        Qout[(size_t)r * DDIM + c] = f2bf(y2);
      }
    }
  }
}

// ---- per-edge: agg[dst] += norm * (A'[src] + Q2[dst]); one wave per edge
__global__ __launch_bounds__(256) void edge_agg(
    const int* __restrict__ src, const int* __restrict__ dst,
    const float* __restrict__ nrm,
    const unsigned short* __restrict__ Asrc,
    const unsigned short* __restrict__ Qdst,
    float* __restrict__ agg, int nE) {
  const int lane = threadIdx.x & 63;
  int w = (blockIdx.x * blockDim.x + threadIdx.x) >> 6;
  const int nW = (gridDim.x * blockDim.x) >> 6;
  for (int e = w; e < nE; e += nW) {
    const int s = src[e], d = dst[e];
    const float nm = nrm[e];
    unsigned av = ((const unsigned*)(Asrc + (size_t)s * DDIM))[lane];
    unsigned qv = ((const unsigned*)(Qdst + (size_t)d * DDIM))[lane];
    float m0 = nm * (bf2f((unsigned short)(av & 0xffffu)) + bf2f((unsigned short)(qv & 0xffffu)));
    float m1 = nm * (bf2f((unsigned short)(av >> 16))     + bf2f((unsigned short)(qv >> 16)));
    float* o = agg + (size_t)d * DDIM + lane * 2;
    atomicAdd(o, m0);
    atomicAdd(o + 1, m1);
  }
}

// ---- in-place leaky-relu + L2 normalize, one wave per row
__global__ __launch_bounds__(256) void finalize(float* __restrict__ h, int nrows) {
  const int lane = threadIdx.x & 63;
  int w = (blockIdx.x * blockDim.x + threadIdx.x) >> 6;
  const int nW = (gridDim.x * blockDim.x) >> 6;
  for (int r = w; r < nrows; r += nW) {
    float* p = h + (size_t)r * DDIM + lane * 2;
    float v0 = p[0], v1 = p[1];
    v0 = v0 > 0.f ? v0 : 0.2f * v0;
    v1 = v1 > 0.f ? v1 : 0.2f * v1;
    float s = v0 * v0 + v1 * v1;
#pragma unroll
    for (int off = 32; off; off >>= 1) s += __shfl_xor(s, off);
    float n = sqrtf(s);
    float sc = 1.0f / fmaxf(n, 1e-12f);
    p[0] = v0 * sc;
    p[1] = v1 * sc;
  }
}

extern "C" void kernel_launch(void* const* d_in, const int* in_sizes, int n_in,
                              void* d_out, int out_size, void* d_ws, size_t ws_size,
                              hipStream_t stream) {
  const float* x_user  = (const float*)d_in[0];
  const float* x_item  = (const float*)d_in[1];
  const float* W1      = (const float*)d_in[2];
  const float* b1      = (const float*)d_in[3];
  const float* W2      = (const float*)d_in[4];
  const float* b2      = (const float*)d_in[5];
  const int*   src_ui  = (const int*)d_in[6];
  const int*   dst_ui  = (const int*)d_in[7];
  const float* norm_ui = (const float*)d_in[8];
  const int*   src_iu  = (const int*)d_in[9];
  const int*   dst_iu  = (const int*)d_in[10];
  const float* norm_iu = (const float*)d_in[11];

  const int NUr   = in_sizes[0] / DDIM;   // 100000
  const int NIr   = in_sizes[1] / DDIM;   // 50000
  const int nE_ui = in_sizes[6];          // 300000
  const int nE_iu = in_sizes[9];

  float* out    = (float*)d_out;
  float* h_user = out;
  float* h_item = out + (size_t)NUr * DDIM;

  // ws layout (bf16): [W1b|W2b][A'_u][A'_i][Q2_u][Q2_i]  ~= 76.9 MB
  unsigned short* wb = (unsigned short*)d_ws;
  unsigned short* Au = wb + 32768;
  unsigned short* Ai = Au + (size_t)NUr * DDIM;
  unsigned short* Qu = Ai + (size_t)NIr * DDIM;
  unsigned short* Qi = Qu + (size_t)NUr * DDIM;

  convW<<<128, 256, 0, stream>>>(W1, W2, wb);
  proj<<<1024, 256, 0, stream>>>(x_user, NUr / 16, wb, b1, b2, Au, Qu, h_user);
  proj<<<1024, 256, 0, stream>>>(x_item, NIr / 16, wb, b1, b2, Ai, Qi, h_item);
  edge_agg<<<4096, 256, 0, stream>>>(src_ui, dst_ui, norm_ui, Au, Qi, h_item, nE_ui);
  edge_agg<<<4096, 256, 0, stream>>>(src_iu, dst_iu, norm_iu, Ai, Qu, h_user, nE_iu);
  finalize<<<4096, 256, 0, stream>>>(out, NUr + NIr);
}

// Round 2
// 336.498 us; speedup vs baseline: 1.8788x; 1.8788x over previous
//
#include <hip/hip_runtime.h>
#include <hip/hip_bf16.h>
#include <stdint.h>

typedef __attribute__((ext_vector_type(8))) short short8;
typedef __attribute__((ext_vector_type(4))) float f32x4;

#define DDIM 128

__device__ __forceinline__ unsigned short f2bf(float f) {
  union { float f; unsigned u; } v; v.f = f;
  unsigned u = v.u + 0x7FFFu + ((v.u >> 16) & 1u);  // round-to-nearest-even
  return (unsigned short)(u >> 16);
}
__device__ __forceinline__ float bf2f(unsigned short b) {
  union { unsigned u; float f; } v; v.u = ((unsigned)b) << 16;
  return v.f;
}

// ---- weights fp32 -> bf16 staging
__global__ void convW(const float* __restrict__ W1, const float* __restrict__ W2,
                      unsigned short* __restrict__ wb) {
  int i = blockIdx.x * blockDim.x + threadIdx.x;
  if (i < 16384)      wb[i] = f2bf(W1[i]);
  else if (i < 32768) wb[i] = f2bf(W2[i - 16384]);
}

// ---- fused projection (see round 1): Pout=y1+b1 (f32, init of h),
//      Aout=bf16(y1+b1+y2+b2) (src operand), Qout=bf16(y2) (dst operand)
__global__ __launch_bounds__(256) void proj(
    const float* __restrict__ x, int ntiles,
    const unsigned short* __restrict__ wb,
    const float* __restrict__ b1, const float* __restrict__ b2,
    unsigned short* __restrict__ Aout, unsigned short* __restrict__ Qout,
    float* __restrict__ Pout) {
  const int lane  = threadIdx.x & 63;
  const int wid   = threadIdx.x >> 6;
  const int col16 = lane & 15;
  const int kgrp  = lane >> 4;
  const int wavesTotal = gridDim.x * 4;

  for (int t = blockIdx.x * 4 + wid; t < ntiles; t += wavesTotal) {
    const int row = t * 16 + col16;
    f32x4 acc[2][8];
#pragma unroll
    for (int w = 0; w < 2; ++w)
#pragma unroll
      for (int ct = 0; ct < 8; ++ct)
        acc[w][ct] = (f32x4){0.f, 0.f, 0.f, 0.f};

#pragma unroll
    for (int ks = 0; ks < 4; ++ks) {
      const float* xp = x + (size_t)row * DDIM + ks * 32 + kgrp * 8;
      float4 xa = *(const float4*)xp;
      float4 xb = *(const float4*)(xp + 4);
      short8 a;
      a[0] = (short)f2bf(xa.x); a[1] = (short)f2bf(xa.y);
      a[2] = (short)f2bf(xa.z); a[3] = (short)f2bf(xa.w);
      a[4] = (short)f2bf(xb.x); a[5] = (short)f2bf(xb.y);
      a[6] = (short)f2bf(xb.z); a[7] = (short)f2bf(xb.w);
#pragma unroll
      for (int w = 0; w < 2; ++w) {
        const unsigned short* wp = wb + w * 16384;
#pragma unroll
        for (int ct = 0; ct < 8; ++ct) {
          short8 b = *(const short8*)(wp + (size_t)(ct * 16 + col16) * DDIM + ks * 32 + kgrp * 8);
          acc[w][ct] = __builtin_amdgcn_mfma_f32_16x16x32_bf16(a, b, acc[w][ct], 0, 0, 0);
        }
      }
    }

#pragma unroll
    for (int ct = 0; ct < 8; ++ct) {
      const int c = ct * 16 + col16;
      const float bb1 = b1[c], bb2 = b2[c];
#pragma unroll
      for (int i = 0; i < 4; ++i) {
        const int r = t * 16 + kgrp * 4 + i;
        const float y1 = acc[0][ct][i] + bb1;
        const float y2 = acc[1][ct][i];
        Pout[(size_t)r * DDIM + c] = y1;
        Aout[(size_t)r * DDIM + c] = f2bf(y1 + y2 + bb2);
        Qout[(size_t)r * DDIM + c] = f2bf(y2);
      }
    }
  }
}

// ---- CSR build: histogram (deg + norm-sum S)
__global__ void hist(const int* __restrict__ dst, const float* __restrict__ nrm,
                     int nE, int* __restrict__ deg, float* __restrict__ S) {
  int i = blockIdx.x * blockDim.x + threadIdx.x;
  int stride = gridDim.x * blockDim.x;
  for (; i < nE; i += stride) {
    int d = dst[i];
    atomicAdd(&deg[d], 1);
    atomicAdd(&S[d], nrm[i]);
  }
}

// ---- scan step 1: per-1024-block exclusive scan + block total
__global__ __launch_bounds__(1024) void scan1(const int* __restrict__ deg, int n,
                                              int* __restrict__ exsc, int* __restrict__ bsum) {
  __shared__ int wsum[16];
  const int tid = threadIdx.x;
  const int g = blockIdx.x * 1024 + tid;
  const int lane = tid & 63, wv = tid >> 6;
  int v = (g < n) ? deg[g] : 0;
  int x = v;
#pragma unroll
  for (int off = 1; off < 64; off <<= 1) {
    int y = __shfl_up(x, off);
    if (lane >= off) x += y;
  }
  if (lane == 63) wsum[wv] = x;
  __syncthreads();
  if (wv == 0 && lane < 16) {
    int s = wsum[lane];
#pragma unroll
    for (int off = 1; off < 16; off <<= 1) {
      int y = __shfl_up(s, off);
      if (lane >= off) s += y;
    }
    wsum[lane] = s;
  }
  __syncthreads();
  int woff = (wv == 0) ? 0 : wsum[wv - 1];
  int inc = x + woff;
  if (g < n) exsc[g] = inc - v;
  if (tid == 1023) bsum[blockIdx.x] = inc;
}

// ---- scan step 2: exclusive scan of block sums (nb <= 128), single block
__global__ __launch_bounds__(128) void scan2(int* __restrict__ bsum, int nb) {
  __shared__ int tmp[128];
  const int tid = threadIdx.x;
  int v = (tid < nb) ? bsum[tid] : 0;
  int x = v;
  tmp[tid] = v;
  __syncthreads();
#pragma unroll
  for (int off = 1; off < 128; off <<= 1) {
    int y = (tid >= off) ? tmp[tid - off] : 0;
    __syncthreads();
    x += y;
    tmp[tid] = x;
    __syncthreads();
  }
  if (tid < nb) bsum[tid] = x - v;
}

// ---- scan step 3: rowptr/cursor = exsc + block offset
__global__ void scan3(const int* __restrict__ exsc, const int* __restrict__ bsum,
                      int n, int nE, int* __restrict__ rowptr, int* __restrict__ cursor) {
  int g = blockIdx.x * blockDim.x + threadIdx.x;
  if (g < n) {
    int v = exsc[g] + bsum[g >> 10];
    rowptr[g] = v;
    cursor[g] = v;
  }
  if (g == n) rowptr[n] = nE;
}

// ---- CSR fill: payload = (src, norm) 8B
__global__ void fillcsr(const int* __restrict__ src, const int* __restrict__ dst,
                        const float* __restrict__ nrm, int nE,
                        int* __restrict__ cursor, int2* __restrict__ pay) {
  int i = blockIdx.x * blockDim.x + threadIdx.x;
  int stride = gridDim.x * blockDim.x;
  for (; i < nE; i += stride) {
    int d = dst[i];
    int pos = atomicAdd(&cursor[d], 1);
    int2 p;
    p.x = src[i];
    p.y = __float_as_int(nrm[i]);
    pay[pos] = p;
  }
}

// ---- pull aggregation: one wave per dst row, no output atomics
//      h[r] += sum_e norm_e * A'[src_e]  +  S[r] * Q2[r]
__global__ __launch_bounds__(256) void pull(
    const int* __restrict__ rowptr, const int2* __restrict__ pay,
    const unsigned short* __restrict__ A, const unsigned short* __restrict__ Q,
    const float* __restrict__ S, float* __restrict__ h, int nrows) {
  const int lane = threadIdx.x & 63;
  int w = (blockIdx.x * blockDim.x + threadIdx.x) >> 6;
  const int nW = (gridDim.x * blockDim.x) >> 6;
  for (int r = w; r < nrows; r += nW) {
    const int beg = rowptr[r], end = rowptr[r + 1];
    if (beg == end) continue;  // deg==0 => S==0, nothing to add
    float a0 = 0.f, a1 = 0.f;
    for (int e = beg; e < end; ++e) {
      int2 p = pay[e];
      float nm = __int_as_float(p.y);
      unsigned av = ((const unsigned*)(A + (size_t)p.x * DDIM))[lane];
      a0 += nm * bf2f((unsigned short)(av & 0xffffu));
      a1 += nm * bf2f((unsigned short)(av >> 16));
    }
    const float s = S[r];
    unsigned qv = ((const unsigned*)(Q + (size_t)r * DDIM))[lane];
    a0 += s * bf2f((unsigned short)(qv & 0xffffu));
    a1 += s * bf2f((unsigned short)(qv >> 16));
    float* o = h + (size_t)r * DDIM + lane * 2;
    o[0] += a0;
    o[1] += a1;
  }
}

// ---- in-place leaky-relu + L2 normalize, one wave per row
__global__ __launch_bounds__(256) void finalize(float* __restrict__ h, int nrows) {
  const int lane = threadIdx.x & 63;
  int w = (blockIdx.x * blockDim.x + threadIdx.x) >> 6;
  const int nW = (gridDim.x * blockDim.x) >> 6;
  for (int r = w; r < nrows; r += nW) {
    float* p = h + (size_t)r * DDIM + lane * 2;
    float v0 = p[0], v1 = p[1];
    v0 = v0 > 0.f ? v0 : 0.2f * v0;
    v1 = v1 > 0.f ? v1 : 0.2f * v1;
    float s = v0 * v0 + v1 * v1;
#pragma unroll
    for (int off = 32; off; off >>= 1) s += __shfl_xor(s, off);
    float n = sqrtf(s);
    float sc = 1.0f / fmaxf(n, 1e-12f);
    p[0] = v0 * sc;
    p[1] = v1 * sc;
  }
}

extern "C" void kernel_launch(void* const* d_in, const int* in_sizes, int n_in,
                              void* d_out, int out_size, void* d_ws, size_t ws_size,
                              hipStream_t stream) {
  const float* x_user  = (const float*)d_in[0];
  const float* x_item  = (const float*)d_in[1];
  const float* W1      = (const float*)d_in[2];
  const float* b1      = (const float*)d_in[3];
  const float* W2      = (const float*)d_in[4];
  const float* b2      = (const float*)d_in[5];
  const int*   src_ui  = (const int*)d_in[6];
  const int*   dst_ui  = (const int*)d_in[7];
  const float* norm_ui = (const float*)d_in[8];
  const int*   src_iu  = (const int*)d_in[9];
  const int*   dst_iu  = (const int*)d_in[10];
  const float* norm_iu = (const float*)d_in[11];

  const int NUr   = in_sizes[0] / DDIM;   // 100000
  const int NIr   = in_sizes[1] / DDIM;   // 50000
  const int nE_ui = in_sizes[6];          // 300000
  const int nE_iu = in_sizes[9];

  float* out    = (float*)d_out;
  float* h_user = out;
  float* h_item = out + (size_t)NUr * DDIM;

  // ---- workspace layout (bytes)
  char* ws = (char*)d_ws;
  size_t off = 0;
  auto alloc = [&](size_t bytes) { char* p = ws + off; off += (bytes + 15) & ~(size_t)15; return p; };
  unsigned short* wb  = (unsigned short*)alloc(32768 * 2);
  unsigned short* Au  = (unsigned short*)alloc((size_t)NUr * DDIM * 2);
  unsigned short* Ai  = (unsigned short*)alloc((size_t)NIr * DDIM * 2);
  unsigned short* Qu  = (unsigned short*)alloc((size_t)NUr * DDIM * 2);
  unsigned short* Qi  = (unsigned short*)alloc((size_t)NIr * DDIM * 2);
  float* S_u          = (float*)alloc((size_t)NUr * 4);
  float* S_i          = (float*)alloc((size_t)NIr * 4);
  int*   deg          = (int*)alloc((size_t)NUr * 4);           // reused both passes
  int*   exsc         = (int*)alloc((size_t)NUr * 4);
  int*   bsum         = (int*)alloc(128 * 4);
  int*   cursor       = (int*)alloc((size_t)NUr * 4);
  int*   rowptr       = (int*)alloc(((size_t)NUr + 1) * 4);
  int2*  pay          = (int2*)alloc((size_t)(nE_ui > nE_iu ? nE_ui : nE_iu) * 8);

  // zero S_u + S_i (contiguous)
  hipMemsetAsync(S_u, 0, ((size_t)NUr + NIr) * 4, stream);

  convW<<<128, 256, 0, stream>>>(W1, W2, wb);
  proj<<<1024, 256, 0, stream>>>(x_user, NUr / 16, wb, b1, b2, Au, Qu, h_user);
  proj<<<1024, 256, 0, stream>>>(x_item, NIr / 16, wb, b1, b2, Ai, Qi, h_item);

  // ---- pass 1: user -> item (dst space = items, NIr)
  {
    const int n = NIr, nb = (n + 1023) / 1024;
    hipMemsetAsync(deg, 0, (size_t)n * 4, stream);
    hist<<<1024, 256, 0, stream>>>(dst_ui, norm_ui, nE_ui, deg, S_i);
    scan1<<<nb, 1024, 0, stream>>>(deg, n, exsc, bsum);
    scan2<<<1, 128, 0, stream>>>(bsum, nb);
    scan3<<<(n + 256) / 256, 256, 0, stream>>>(exsc, bsum, n, nE_ui, rowptr, cursor);
    fillcsr<<<1024, 256, 0, stream>>>(src_ui, dst_ui, norm_ui, nE_ui, cursor, pay);
    pull<<<((size_t)n * 64 + 255) / 256, 256, 0, stream>>>(rowptr, pay, Au, Qi, S_i, h_item, n);
  }

  // ---- pass 2: item -> user (dst space = users, NUr)
  {
    const int n = NUr, nb = (n + 1023) / 1024;
    hipMemsetAsync(deg, 0, (size_t)n * 4, stream);
    hist<<<1024, 256, 0, stream>>>(dst_iu, norm_iu, nE_iu, deg, S_u);
    scan1<<<nb, 1024, 0, stream>>>(deg, n, exsc, bsum);
    scan2<<<1, 128, 0, stream>>>(bsum, nb);
    scan3<<<(n + 256) / 256, 256, 0, stream>>>(exsc, bsum, n, nE_iu, rowptr, cursor);
    fillcsr<<<1024, 256, 0, stream>>>(src_iu, dst_iu, norm_iu, nE_iu, cursor, pay);
    pull<<<((size_t)n * 64 + 255) / 256, 256, 0, stream>>>(rowptr, pay, Ai, Qu, S_u, h_user, n);
  }

  finalize<<<4096, 256, 0, stream>>>(out, NUr + NIr);
}

// Round 3
// 295.889 us; speedup vs baseline: 2.1367x; 1.1372x over previous
//
#include <hip/hip_runtime.h>
#include <hip/hip_bf16.h>
#include <stdint.h>

typedef __attribute__((ext_vector_type(8))) short short8;
typedef __attribute__((ext_vector_type(4))) float f32x4;

#define DDIM 128

__device__ __forceinline__ unsigned short f2bf(float f) {
  union { float f; unsigned u; } v; v.f = f;
  unsigned u = v.u + 0x7FFFu + ((v.u >> 16) & 1u);  // RNE
  return (unsigned short)(u >> 16);
}
__device__ __forceinline__ float bf2f(unsigned short b) {
  union { unsigned u; float f; } v; v.u = ((unsigned)b) << 16;
  return v.f;
}

// ---- weights fp32 -> bf16 staging
__global__ void convW(const float* __restrict__ W1, const float* __restrict__ W2,
                      unsigned short* __restrict__ wb) {
  int i = blockIdx.x * blockDim.x + threadIdx.x;
  if (i < 16384)      wb[i] = f2bf(W1[i]);
  else if (i < 32768) wb[i] = f2bf(W2[i - 16384]);
}

// ---- fused projection, 2 waves per 16-row tile (64 cols each):
//      Pout = y1+b1 (f32, init of h), Aout = bf16(y1+b1+y2+b2), Qout = bf16(y2)
__global__ __launch_bounds__(256) void proj(
    const float* __restrict__ x, int ntiles,
    const unsigned short* __restrict__ wb,
    const float* __restrict__ b1, const float* __restrict__ b2,
    unsigned short* __restrict__ Aout, unsigned short* __restrict__ Qout,
    float* __restrict__ Pout) {
  const int lane  = threadIdx.x & 63;
  const int wid   = threadIdx.x >> 6;
  const int col16 = lane & 15;
  const int kgrp  = lane >> 4;
  const int jobsTotal = ntiles * 2;      // job = (tile, col-half)
  const int jstride   = gridDim.x * 4;

  for (int j = blockIdx.x * 4 + wid; j < jobsTotal; j += jstride) {
    const int t  = j >> 1;
    const int hf = j & 1;
    const int row = t * 16 + col16;
    f32x4 acc[2][4];
#pragma unroll
    for (int w = 0; w < 2; ++w)
#pragma unroll
      for (int ct = 0; ct < 4; ++ct)
        acc[w][ct] = (f32x4){0.f, 0.f, 0.f, 0.f};

#pragma unroll
    for (int ks = 0; ks < 4; ++ks) {
      const float* xp = x + (size_t)row * DDIM + ks * 32 + kgrp * 8;
      float4 xa = *(const float4*)xp;
      float4 xb = *(const float4*)(xp + 4);
      short8 a;
      a[0] = (short)f2bf(xa.x); a[1] = (short)f2bf(xa.y);
      a[2] = (short)f2bf(xa.z); a[3] = (short)f2bf(xa.w);
      a[4] = (short)f2bf(xb.x); a[5] = (short)f2bf(xb.y);
      a[6] = (short)f2bf(xb.z); a[7] = (short)f2bf(xb.w);
#pragma unroll
      for (int w = 0; w < 2; ++w) {
        const unsigned short* wp = wb + w * 16384;
#pragma unroll
        for (int ct = 0; ct < 4; ++ct) {
          const int c = hf * 64 + ct * 16 + col16;
          short8 b = *(const short8*)(wp + (size_t)c * DDIM + ks * 32 + kgrp * 8);
          acc[w][ct] = __builtin_amdgcn_mfma_f32_16x16x32_bf16(a, b, acc[w][ct], 0, 0, 0);
        }
      }
    }

#pragma unroll
    for (int ct = 0; ct < 4; ++ct) {
      const int c = hf * 64 + ct * 16 + col16;
      const float bb1 = b1[c], bb2 = b2[c];
#pragma unroll
      for (int i = 0; i < 4; ++i) {
        const int r = t * 16 + kgrp * 4 + i;
        const float y1 = acc[0][ct][i] + bb1;
        const float y2 = acc[1][ct][i];
        Pout[(size_t)r * DDIM + c] = y1;
        Aout[(size_t)r * DDIM + c] = f2bf(y1 + y2 + bb2);
        Qout[(size_t)r * DDIM + c] = f2bf(y2);
      }
    }
  }
}

// ---- combined histogram over both edge types (dst rows: user 0..NU-1, item NU..)
__global__ void hist(const int* __restrict__ dst_ui, const float* __restrict__ nrm_ui, int nE_ui,
                     const int* __restrict__ dst_iu, const float* __restrict__ nrm_iu, int nE_iu,
                     int NU, int* __restrict__ deg, float* __restrict__ S) {
  int i = blockIdx.x * blockDim.x + threadIdx.x;
  int stride = gridDim.x * blockDim.x;
  int nTot = nE_ui + nE_iu;
  for (; i < nTot; i += stride) {
    int d; float nm;
    if (i < nE_ui) { d = NU + dst_ui[i]; nm = nrm_ui[i]; }
    else           { d = dst_iu[i - nE_ui]; nm = nrm_iu[i - nE_ui]; }
    atomicAdd(&deg[d], 1);
    atomicAdd(&S[d], nm);
  }
}

// ---- scan step 1: per-1024-block exclusive scan + block total
__global__ __launch_bounds__(1024) void scan1(const int* __restrict__ deg, int n,
                                              int* __restrict__ exsc, int* __restrict__ bsum) {
  __shared__ int wsum[16];
  const int tid = threadIdx.x;
  const int g = blockIdx.x * 1024 + tid;
  const int lane = tid & 63, wv = tid >> 6;
  int v = (g < n) ? deg[g] : 0;
  int x = v;
#pragma unroll
  for (int off = 1; off < 64; off <<= 1) {
    int y = __shfl_up(x, off);
    if (lane >= off) x += y;
  }
  if (lane == 63) wsum[wv] = x;
  __syncthreads();
  if (wv == 0 && lane < 16) {
    int s = wsum[lane];
#pragma unroll
    for (int off = 1; off < 16; off <<= 1) {
      int y = __shfl_up(s, off);
      if (lane >= off) s += y;
    }
    wsum[lane] = s;
  }
  __syncthreads();
  int woff = (wv == 0) ? 0 : wsum[wv - 1];
  int inc = x + woff;
  if (g < n) exsc[g] = inc - v;
  if (tid == 1023) bsum[blockIdx.x] = inc;
}

// ---- scan step 2: exclusive scan of block sums (nb <= 256), single block
__global__ __launch_bounds__(256) void scan2(int* __restrict__ bsum, int nb) {
  __shared__ int tmp[256];
  const int tid = threadIdx.x;
  int v = (tid < nb) ? bsum[tid] : 0;
  int x = v;
  tmp[tid] = v;
  __syncthreads();
#pragma unroll
  for (int off = 1; off < 256; off <<= 1) {
    int y = (tid >= off) ? tmp[tid - off] : 0;
    __syncthreads();
    x += y;
    tmp[tid] = x;
    __syncthreads();
  }
  if (tid < nb) bsum[tid] = x - v;
}

// ---- scan step 3: rowptr/cursor = exsc + block offset
__global__ void scan3(const int* __restrict__ exsc, const int* __restrict__ bsum,
                      int n, int nETot, int* __restrict__ rowptr, int* __restrict__ cursor) {
  int g = blockIdx.x * blockDim.x + threadIdx.x;
  if (g < n) {
    int v = exsc[g] + bsum[g >> 10];
    rowptr[g] = v;
    cursor[g] = v;
  }
  if (g == n) rowptr[n] = nETot;
}

// ---- CSR fill (both edge types): payload = (src, norm) 8B
__global__ void fillcsr(const int* __restrict__ src_ui, const int* __restrict__ dst_ui,
                        const float* __restrict__ nrm_ui, int nE_ui,
                        const int* __restrict__ src_iu, const int* __restrict__ dst_iu,
                        const float* __restrict__ nrm_iu, int nE_iu,
                        int NU, int* __restrict__ cursor, int2* __restrict__ pay) {
  int i = blockIdx.x * blockDim.x + threadIdx.x;
  int stride = gridDim.x * blockDim.x;
  int nTot = nE_ui + nE_iu;
  for (; i < nTot; i += stride) {
    int d, s; float nm;
    if (i < nE_ui) { d = NU + dst_ui[i]; s = src_ui[i]; nm = nrm_ui[i]; }
    else { int k = i - nE_ui; d = dst_iu[k]; s = src_iu[k]; nm = nrm_iu[k]; }
    int pos = atomicAdd(&cursor[d], 1);
    int2 p; p.x = s; p.y = __float_as_int(nm);
    pay[pos] = p;
  }
}

// ---- pull + leaky-relu + L2 normalize, one wave per output row
//      h[r] = P[r](already in out) + sum_e norm_e*A[src_e] + S[r]*Q[r]; then activate+normalize
__global__ __launch_bounds__(256) void pullfin(
    const int* __restrict__ rowptr, const int2* __restrict__ pay,
    const unsigned short* __restrict__ Au, const unsigned short* __restrict__ Ai,
    const unsigned short* __restrict__ Qc, const float* __restrict__ S,
    float* __restrict__ out, int NU, int ntot) {
  const int lane = threadIdx.x & 63;
  int w = (blockIdx.x * blockDim.x + threadIdx.x) >> 6;
  const int nW = (gridDim.x * blockDim.x) >> 6;
  for (int r = w; r < ntot; r += nW) {
    const unsigned short* A = (r < NU) ? Ai : Au;  // user rows gather item-A, vice versa
    const int beg = rowptr[r], end = rowptr[r + 1];
    float a0 = 0.f, a1 = 0.f, c0 = 0.f, c1 = 0.f;
    int e = beg;
    for (; e + 1 < end; e += 2) {
      int2 p0 = pay[e], p1 = pay[e + 1];
      unsigned av0 = ((const unsigned*)(A + (size_t)p0.x * DDIM))[lane];
      unsigned av1 = ((const unsigned*)(A + (size_t)p1.x * DDIM))[lane];
      float n0 = __int_as_float(p0.y), n1 = __int_as_float(p1.y);
      a0 += n0 * bf2f((unsigned short)(av0 & 0xffffu));
      a1 += n0 * bf2f((unsigned short)(av0 >> 16));
      c0 += n1 * bf2f((unsigned short)(av1 & 0xffffu));
      c1 += n1 * bf2f((unsigned short)(av1 >> 16));
    }
    if (e < end) {
      int2 p0 = pay[e];
      unsigned av0 = ((const unsigned*)(A + (size_t)p0.x * DDIM))[lane];
      float n0 = __int_as_float(p0.y);
      a0 += n0 * bf2f((unsigned short)(av0 & 0xffffu));
      a1 += n0 * bf2f((unsigned short)(av0 >> 16));
    }
    a0 += c0; a1 += c1;
    const float s = S[r];
    unsigned qv = ((const unsigned*)(Qc + (size_t)r * DDIM))[lane];
    a0 += s * bf2f((unsigned short)(qv & 0xffffu));
    a1 += s * bf2f((unsigned short)(qv >> 16));

    float2* o = (float2*)(out + (size_t)r * DDIM + lane * 2);
    float2 pv = *o;
    float v0 = pv.x + a0, v1 = pv.y + a1;
    v0 = v0 > 0.f ? v0 : 0.2f * v0;
    v1 = v1 > 0.f ? v1 : 0.2f * v1;
    float sq = v0 * v0 + v1 * v1;
#pragma unroll
    for (int off = 32; off; off >>= 1) sq += __shfl_xor(sq, off);
    float sc = 1.0f / fmaxf(sqrtf(sq), 1e-12f);
    float2 res; res.x = v0 * sc; res.y = v1 * sc;
    *o = res;
  }
}

extern "C" void kernel_launch(void* const* d_in, const int* in_sizes, int n_in,
                              void* d_out, int out_size, void* d_ws, size_t ws_size,
                              hipStream_t stream) {
  const float* x_user  = (const float*)d_in[0];
  const float* x_item  = (const float*)d_in[1];
  const float* W1      = (const float*)d_in[2];
  const float* b1      = (const float*)d_in[3];
  const float* W2      = (const float*)d_in[4];
  const float* b2      = (const float*)d_in[5];
  const int*   src_ui  = (const int*)d_in[6];
  const int*   dst_ui  = (const int*)d_in[7];
  const float* norm_ui = (const float*)d_in[8];
  const int*   src_iu  = (const int*)d_in[9];
  const int*   dst_iu  = (const int*)d_in[10];
  const float* norm_iu = (const float*)d_in[11];

  const int NUr   = in_sizes[0] / DDIM;   // 100000
  const int NIr   = in_sizes[1] / DDIM;   // 50000
  const int nE_ui = in_sizes[6];          // 300000
  const int nE_iu = in_sizes[9];
  const int nTot  = NUr + NIr;
  const int nETot = nE_ui + nE_iu;

  float* out = (float*)d_out;             // rows: [h_user (NUr); h_item (NIr)]

  // ---- workspace layout
  char* ws = (char*)d_ws;
  size_t off = 0;
  auto alloc = [&](size_t bytes) { char* p = ws + off; off += (bytes + 15) & ~(size_t)15; return p; };
  unsigned short* wb  = (unsigned short*)alloc(32768 * 2);
  unsigned short* Au  = (unsigned short*)alloc((size_t)NUr * DDIM * 2);
  unsigned short* Ai  = (unsigned short*)alloc((size_t)NIr * DDIM * 2);
  unsigned short* Qc  = (unsigned short*)alloc((size_t)nTot * DDIM * 2); // [Qu; Qi]
  float* S            = (float*)alloc((size_t)nTot * 4);
  int*   deg          = (int*)alloc((size_t)nTot * 4);
  int*   exsc         = (int*)alloc((size_t)nTot * 4);
  int*   bsum         = (int*)alloc(256 * 4);
  int*   cursor       = (int*)alloc((size_t)nTot * 4);
  int*   rowptr       = (int*)alloc(((size_t)nTot + 1) * 4);
  int2*  pay          = (int2*)alloc((size_t)nETot * 8);

  // zero S and deg (adjacent allocations)
  hipMemsetAsync(S, 0, (size_t)nTot * 8, stream);

  convW<<<128, 256, 0, stream>>>(W1, W2, wb);
  proj<<<3125, 256, 0, stream>>>(x_user, NUr / 16, wb, b1, b2, Au, Qc, out);
  proj<<<1563, 256, 0, stream>>>(x_item, NIr / 16, wb, b1, b2, Ai,
                                 Qc + (size_t)NUr * DDIM, out + (size_t)NUr * DDIM);

  const int nb = (nTot + 1023) / 1024;    // 147
  hist<<<2048, 256, 0, stream>>>(dst_ui, norm_ui, nE_ui, dst_iu, norm_iu, nE_iu, NUr, deg, S);
  scan1<<<nb, 1024, 0, stream>>>(deg, nTot, exsc, bsum);
  scan2<<<1, 256, 0, stream>>>(bsum, nb);
  scan3<<<(nTot + 256) / 256, 256, 0, stream>>>(exsc, bsum, nTot, nETot, rowptr, cursor);
  fillcsr<<<2048, 256, 0, stream>>>(src_ui, dst_ui, norm_ui, nE_ui,
                                    src_iu, dst_iu, norm_iu, nE_iu, NUr, cursor, pay);
  pullfin<<<(nTot + 3) / 4, 256, 0, stream>>>(rowptr, pay, Au, Ai, Qc, S, out, NUr, nTot);
}

// Round 5
// 242.416 us; speedup vs baseline: 2.6080x; 1.2206x over previous
//
#include <hip/hip_runtime.h>
#include <hip/hip_bf16.h>
#include <stdint.h>

typedef __attribute__((ext_vector_type(8))) short short8;
typedef __attribute__((ext_vector_type(4))) float f32x4;

#define DDIM 128

__device__ __forceinline__ unsigned short f2bf(float f) {
  union { float f; unsigned u; } v; v.f = f;
  unsigned u = v.u + 0x7FFFu + ((v.u >> 16) & 1u);  // RNE
  return (unsigned short)(u >> 16);
}
__device__ __forceinline__ float bf2f(unsigned short b) {
  union { unsigned u; float f; } v; v.u = ((unsigned)b) << 16;
  return v.f;
}

// ---- weights fp32 -> bf16 staging: wb = [W1 rows; W2 rows] = [256][128]
__global__ void convW(const float* __restrict__ W1, const float* __restrict__ W2,
                      unsigned short* __restrict__ wb) {
  int i = blockIdx.x * blockDim.x + threadIdx.x;
  if (i < 16384)      wb[i] = f2bf(W1[i]);
  else if (i < 32768) wb[i] = f2bf(W2[i - 16384]);
}

// ---- proj v3: coalesced LDS-staged, W in registers.
// Block = 4 waves, 64-row tile, wave w owns cols [w*32, w*32+32) for BOTH W1,W2.
// Writes ONLY  A = bf16(y1+b1+y2+b2)  and  Q = bf16(y2)   (P reconstructed later).
__global__ __launch_bounds__(256) void proj(
    const float* __restrict__ x, int nrows,
    const unsigned short* __restrict__ wb,
    const float* __restrict__ b1, const float* __restrict__ b2,
    unsigned short* __restrict__ Aout, unsigned short* __restrict__ Qout) {
  __shared__ unsigned short xs[64 * DDIM];   // 16 KB, XOR-swizzled
  const int tid   = threadIdx.x;
  const int lane  = tid & 63;
  const int wv    = tid >> 6;
  const int col16 = lane & 15;
  const int kgrp  = lane >> 4;

  // preload W fragments (one-time per block): m=W1/W2, ct=col-subtile, ks=K-step
  short8 wf[2][2][4];
#pragma unroll
  for (int m = 0; m < 2; ++m)
#pragma unroll
    for (int ct = 0; ct < 2; ++ct) {
      const int c = m * 128 + wv * 32 + ct * 16 + col16;
#pragma unroll
      for (int ks = 0; ks < 4; ++ks)
        wf[m][ct][ks] = *(const short8*)(wb + (size_t)c * DDIM + ks * 32 + kgrp * 8);
    }
  float b1c[2], b2c[2];
#pragma unroll
  for (int ct = 0; ct < 2; ++ct) {
    const int c = wv * 32 + ct * 16 + col16;
    b1c[ct] = b1[c];
    b2c[ct] = b2[c];
  }

  const int ntiles = (nrows + 63) >> 6;
  for (int t = blockIdx.x; t < ntiles; t += gridDim.x) {
    const int r0 = t * 64;
    __syncthreads();  // protect xs reads of previous iteration
    // ---- stage 64x128 f32 -> bf16 LDS, coalesced
#pragma unroll
    for (int i = 0; i < 8; ++i) {
      const int flat = i * 1024 + tid * 4;
      const int rr = flat >> 7, cc = flat & 127;
      float4 v;
      if (r0 + rr < nrows) v = *(const float4*)(x + (size_t)(r0 + rr) * DDIM + cc);
      else                 v = make_float4(0.f, 0.f, 0.f, 0.f);
      uint2 pk;
      pk.x = ((unsigned)f2bf(v.y) << 16) | f2bf(v.x);
      pk.y = ((unsigned)f2bf(v.w) << 16) | f2bf(v.z);
      const int byte = (rr * 256 + cc * 2) ^ ((rr & 7) << 4);
      *(uint2*)((char*)xs + byte) = pk;
    }
    __syncthreads();

    // ---- MFMA: acc[rt][m][ct]
    f32x4 acc[4][2][2];
#pragma unroll
    for (int rt = 0; rt < 4; ++rt)
#pragma unroll
      for (int m = 0; m < 2; ++m)
#pragma unroll
        for (int ct = 0; ct < 2; ++ct)
          acc[rt][m][ct] = (f32x4){0.f, 0.f, 0.f, 0.f};

#pragma unroll
    for (int ks = 0; ks < 4; ++ks) {
#pragma unroll
      for (int rt = 0; rt < 4; ++rt) {
        const int rr = rt * 16 + col16;
        const int byte = (rr * 256 + (ks * 64 + kgrp * 16)) ^ ((rr & 7) << 4);
        short8 a = *(const short8*)((char*)xs + byte);
#pragma unroll
        for (int m = 0; m < 2; ++m)
#pragma unroll
          for (int ct = 0; ct < 2; ++ct)
            acc[rt][m][ct] = __builtin_amdgcn_mfma_f32_16x16x32_bf16(a, wf[m][ct][ks], acc[rt][m][ct], 0, 0, 0);
      }
    }

    // ---- epilogue
#pragma unroll
    for (int rt = 0; rt < 4; ++rt)
#pragma unroll
      for (int ct = 0; ct < 2; ++ct) {
        const int c = wv * 32 + ct * 16 + col16;
#pragma unroll
        for (int i = 0; i < 4; ++i) {
          const int r = r0 + rt * 16 + kgrp * 4 + i;
          if (r < nrows) {
            const float y1 = acc[rt][0][ct][i] + b1c[ct];
            const float y2 = acc[rt][1][ct][i];
            Aout[(size_t)r * DDIM + c] = f2bf(y1 + y2 + b2c[ct]);
            Qout[(size_t)r * DDIM + c] = f2bf(y2);
          }
        }
      }
  }
}

// ---- combined histogram over both edge types (dst rows: user 0..NU-1, item NU..)
__global__ void hist(const int* __restrict__ dst_ui, const float* __restrict__ nrm_ui, int nE_ui,
                     const int* __restrict__ dst_iu, const float* __restrict__ nrm_iu, int nE_iu,
                     int NU, int* __restrict__ deg, float* __restrict__ S) {
  int i = blockIdx.x * blockDim.x + threadIdx.x;
  int stride = gridDim.x * blockDim.x;
  int nTot = nE_ui + nE_iu;
  for (; i < nTot; i += stride) {
    int d; float nm;
    if (i < nE_ui) { d = NU + dst_ui[i]; nm = nrm_ui[i]; }
    else           { d = dst_iu[i - nE_ui]; nm = nrm_iu[i - nE_ui]; }
    atomicAdd(&deg[d], 1);
    atomicAdd(&S[d], nm);
  }
}

__global__ __launch_bounds__(1024) void scan1(const int* __restrict__ deg, int n,
                                              int* __restrict__ exsc, int* __restrict__ bsum) {
  __shared__ int wsum[16];
  const int tid = threadIdx.x;
  const int g = blockIdx.x * 1024 + tid;
  const int lane = tid & 63, wv = tid >> 6;
  int v = (g < n) ? deg[g] : 0;
  int x = v;
#pragma unroll
  for (int off = 1; off < 64; off <<= 1) {
    int y = __shfl_up(x, off);
    if (lane >= off) x += y;
  }
  if (lane == 63) wsum[wv] = x;
  __syncthreads();
  if (wv == 0 && lane < 16) {
    int s = wsum[lane];
#pragma unroll
    for (int off = 1; off < 16; off <<= 1) {
      int y = __shfl_up(s, off);
      if (lane >= off) s += y;
    }
    wsum[lane] = s;
  }
  __syncthreads();
  int woff = (wv == 0) ? 0 : wsum[wv - 1];
  int inc = x + woff;
  if (g < n) exsc[g] = inc - v;
  if (tid == 1023) bsum[blockIdx.x] = inc;
}

__global__ __launch_bounds__(256) void scan2(int* __restrict__ bsum, int nb) {
  __shared__ int tmp[256];
  const int tid = threadIdx.x;
  int v = (tid < nb) ? bsum[tid] : 0;
  int x = v;
  tmp[tid] = v;
  __syncthreads();
#pragma unroll
  for (int off = 1; off < 256; off <<= 1) {
    int y = (tid >= off) ? tmp[tid - off] : 0;
    __syncthreads();
    x += y;
    tmp[tid] = x;
    __syncthreads();
  }
  if (tid < nb) bsum[tid] = x - v;
}

__global__ void scan3(const int* __restrict__ exsc, const int* __restrict__ bsum,
                      int n, int nETot, int* __restrict__ rowptr, int* __restrict__ cursor) {
  int g = blockIdx.x * blockDim.x + threadIdx.x;
  if (g < n) {
    int v = exsc[g] + bsum[g >> 10];
    rowptr[g] = v;
    cursor[g] = v;
  }
  if (g == n) rowptr[n] = nETot;
}

__global__ void fillcsr(const int* __restrict__ src_ui, const int* __restrict__ dst_ui,
                        const float* __restrict__ nrm_ui, int nE_ui,
                        const int* __restrict__ src_iu, const int* __restrict__ dst_iu,
                        const float* __restrict__ nrm_iu, int nE_iu,
                        int NU, int* __restrict__ cursor, int2* __restrict__ pay) {
  int i = blockIdx.x * blockDim.x + threadIdx.x;
  int stride = gridDim.x * blockDim.x;
  int nTot = nE_ui + nE_iu;
  for (; i < nTot; i += stride) {
    int d, s; float nm;
    if (i < nE_ui) { d = NU + dst_ui[i]; s = src_ui[i]; nm = nrm_ui[i]; }
    else { int k = i - nE_ui; d = dst_iu[k]; s = src_iu[k]; nm = nrm_iu[k]; }
    int pos = atomicAdd(&cursor[d], 1);
    int2 p; p.x = s; p.y = __float_as_int(nm);
    pay[pos] = p;
  }
}

// ---- pull + self-reconstruction + leaky-relu + L2 normalize; out is WRITE-ONLY.
// h[r] = (A_self[r] - Q[r] - b2) + S[r]*Q[r] + sum_e norm_e * A_gather[src_e]
//      = A_self[r] + (S[r]-1)*Q[r] - b2 + gather
__global__ __launch_bounds__(256) void pullfin(
    const int* __restrict__ rowptr, const int2* __restrict__ pay,
    const unsigned short* __restrict__ Ac,   // [Au; Ai] contiguous (self rows)
    const unsigned short* __restrict__ Au, const unsigned short* __restrict__ Ai,
    const unsigned short* __restrict__ Qc, const float* __restrict__ S,
    const float* __restrict__ b2,
    float* __restrict__ out, int NU, int ntot) {
  const int lane = threadIdx.x & 63;
  const float b2v0 = b2[lane * 2], b2v1 = b2[lane * 2 + 1];
  int w = (blockIdx.x * blockDim.x + threadIdx.x) >> 6;
  const int nW = (gridDim.x * blockDim.x) >> 6;
  for (int r = w; r < ntot; r += nW) {
    const unsigned short* Ag = (r < NU) ? Ai : Au;   // gather the OTHER ntype
    const int beg = rowptr[r], end = rowptr[r + 1];
    float a0 = 0.f, a1 = 0.f, c0 = 0.f, c1 = 0.f;
    int e = beg;
    for (; e + 1 < end; e += 2) {
      int2 p0 = pay[e], p1 = pay[e + 1];
      unsigned av0 = ((const unsigned*)(Ag + (size_t)p0.x * DDIM))[lane];
      unsigned av1 = ((const unsigned*)(Ag + (size_t)p1.x * DDIM))[lane];
      float n0 = __int_as_float(p0.y), n1 = __int_as_float(p1.y);
      a0 += n0 * bf2f((unsigned short)(av0 & 0xffffu));
      a1 += n0 * bf2f((unsigned short)(av0 >> 16));
      c0 += n1 * bf2f((unsigned short)(av1 & 0xffffu));
      c1 += n1 * bf2f((unsigned short)(av1 >> 16));
    }
    if (e < end) {
      int2 p0 = pay[e];
      unsigned av0 = ((const unsigned*)(Ag + (size_t)p0.x * DDIM))[lane];
      float n0 = __int_as_float(p0.y);
      a0 += n0 * bf2f((unsigned short)(av0 & 0xffffu));
      a1 += n0 * bf2f((unsigned short)(av0 >> 16));
    }
    a0 += c0; a1 += c1;

    unsigned av = ((const unsigned*)(Ac + (size_t)r * DDIM))[lane];
    unsigned qv = ((const unsigned*)(Qc + (size_t)r * DDIM))[lane];
    const float s1 = S[r] - 1.0f;
    float v0 = bf2f((unsigned short)(av & 0xffffu)) + s1 * bf2f((unsigned short)(qv & 0xffffu)) - b2v0 + a0;
    float v1 = bf2f((unsigned short)(av >> 16))     + s1 * bf2f((unsigned short)(qv >> 16))     - b2v1 + a1;

    v0 = v0 > 0.f ? v0 : 0.2f * v0;
    v1 = v1 > 0.f ? v1 : 0.2f * v1;
    float sq = v0 * v0 + v1 * v1;
#pragma unroll
    for (int off = 32; off; off >>= 1) sq += __shfl_xor(sq, off);
    float sc = 1.0f / fmaxf(sqrtf(sq), 1e-12f);
    float2 res; res.x = v0 * sc; res.y = v1 * sc;
    *(float2*)(out + (size_t)r * DDIM + lane * 2) = res;
  }
}

extern "C" void kernel_launch(void* const* d_in, const int* in_sizes, int n_in,
                              void* d_out, int out_size, void* d_ws, size_t ws_size,
                              hipStream_t stream) {
  const float* x_user  = (const float*)d_in[0];
  const float* x_item  = (const float*)d_in[1];
  const float* W1      = (const float*)d_in[2];
  const float* b1      = (const float*)d_in[3];
  const float* W2      = (const float*)d_in[4];
  const float* b2      = (const float*)d_in[5];
  const int*   src_ui  = (const int*)d_in[6];
  const int*   dst_ui  = (const int*)d_in[7];
  const float* norm_ui = (const float*)d_in[8];
  const int*   src_iu  = (const int*)d_in[9];
  const int*   dst_iu  = (const int*)d_in[10];
  const float* norm_iu = (const float*)d_in[11];

  const int NUr   = in_sizes[0] / DDIM;   // 100000
  const int NIr   = in_sizes[1] / DDIM;   // 50000
  const int nE_ui = in_sizes[6];          // 300000
  const int nE_iu = in_sizes[9];
  const int nTot  = NUr + NIr;
  const int nETot = nE_ui + nE_iu;

  float* out = (float*)d_out;             // rows: [h_user (NUr); h_item (NIr)]

  // ---- workspace layout
  char* ws = (char*)d_ws;
  size_t off = 0;
  auto alloc = [&](size_t bytes) { char* p = ws + off; off += (bytes + 15) & ~(size_t)15; return p; };
  unsigned short* wb  = (unsigned short*)alloc(32768 * 2);
  unsigned short* Ac  = (unsigned short*)alloc((size_t)nTot * DDIM * 2);  // [Au; Ai]
  unsigned short* Qc  = (unsigned short*)alloc((size_t)nTot * DDIM * 2);  // [Qu; Qi]
  float* S            = (float*)alloc((size_t)nTot * 4);
  int*   deg          = (int*)alloc((size_t)nTot * 4);
  int*   exsc         = (int*)alloc((size_t)nTot * 4);
  int*   bsum         = (int*)alloc(256 * 4);
  int*   cursor       = (int*)alloc((size_t)nTot * 4);
  int*   rowptr       = (int*)alloc(((size_t)nTot + 1) * 4);
  int2*  pay          = (int2*)alloc((size_t)nETot * 8);

  unsigned short* Au = Ac;
  unsigned short* Ai = Ac + (size_t)NUr * DDIM;

  // zero S and deg (contiguous allocations)
  (void)hipMemsetAsync(S, 0, (size_t)nTot * 8, stream);

  convW<<<128, 256, 0, stream>>>(W1, W2, wb);
  proj<<<1563, 256, 0, stream>>>(x_user, NUr, wb, b1, b2, Au, Qc);
  proj<<<782, 256, 0, stream>>>(x_item, NIr, wb, b1, b2, Ai, Qc + (size_t)NUr * DDIM);

  const int nb = (nTot + 1023) / 1024;    // 147
  hist<<<2048, 256, 0, stream>>>(dst_ui, norm_ui, nE_ui, dst_iu, norm_iu, nE_iu, NUr, deg, S);
  scan1<<<nb, 1024, 0, stream>>>(deg, nTot, exsc, bsum);
  scan2<<<1, 256, 0, stream>>>(bsum, nb);
  scan3<<<(nTot + 256) / 256, 256, 0, stream>>>(exsc, bsum, nTot, nETot, rowptr, cursor);
  fillcsr<<<2048, 256, 0, stream>>>(src_ui, dst_ui, norm_ui, nE_ui,
                                    src_iu, dst_iu, norm_iu, nE_iu, NUr, cursor, pay);
  pullfin<<<(nTot + 3) / 4, 256, 0, stream>>>(rowptr, pay, Ac, Au, Ai, Qc, S, b2, out, NUr, nTot);
}

// Round 7
// 224.786 us; speedup vs baseline: 2.8125x; 1.0784x over previous
//
#include <hip/hip_runtime.h>
#include <hip/hip_bf16.h>
#include <stdint.h>

typedef __attribute__((ext_vector_type(8))) short short8;
typedef __attribute__((ext_vector_type(4))) float f32x4;

#define DDIM 128

__device__ __forceinline__ unsigned short f2bf(float f) {
  union { float f; unsigned u; } v; v.f = f;
  unsigned u = v.u + 0x7FFFu + ((v.u >> 16) & 1u);  // RNE
  return (unsigned short)(u >> 16);
}
__device__ __forceinline__ float bf2f(unsigned short b) {
  union { unsigned u; float f; } v; v.u = ((unsigned)b) << 16;
  return v.f;
}

// ---- weights fp32 -> bf16 staging: wb = [W1 rows; W2 rows] = [256][128]
__global__ void convW(const float* __restrict__ W1, const float* __restrict__ W2,
                      unsigned short* __restrict__ wb) {
  int i = blockIdx.x * blockDim.x + threadIdx.x;
  if (i < 16384)      wb[i] = f2bf(W1[i]);
  else if (i < 32768) wb[i] = f2bf(W2[i - 16384]);
}

// ---- proj v3: coalesced LDS-staged, W in registers.
__global__ __launch_bounds__(256) void proj(
    const float* __restrict__ x, int nrows,
    const unsigned short* __restrict__ wb,
    const float* __restrict__ b1, const float* __restrict__ b2,
    unsigned short* __restrict__ Aout, unsigned short* __restrict__ Qout) {
  __shared__ unsigned short xs[64 * DDIM];   // 16 KB, XOR-swizzled
  const int tid   = threadIdx.x;
  const int lane  = tid & 63;
  const int wv    = tid >> 6;
  const int col16 = lane & 15;
  const int kgrp  = lane >> 4;

  short8 wf[2][2][4];
#pragma unroll
  for (int m = 0; m < 2; ++m)
#pragma unroll
    for (int ct = 0; ct < 2; ++ct) {
      const int c = m * 128 + wv * 32 + ct * 16 + col16;
#pragma unroll
      for (int ks = 0; ks < 4; ++ks)
        wf[m][ct][ks] = *(const short8*)(wb + (size_t)c * DDIM + ks * 32 + kgrp * 8);
    }
  float b1c[2], b2c[2];
#pragma unroll
  for (int ct = 0; ct < 2; ++ct) {
    const int c = wv * 32 + ct * 16 + col16;
    b1c[ct] = b1[c];
    b2c[ct] = b2[c];
  }

  const int ntiles = (nrows + 63) >> 6;
  for (int t = blockIdx.x; t < ntiles; t += gridDim.x) {
    const int r0 = t * 64;
    __syncthreads();
#pragma unroll
    for (int i = 0; i < 8; ++i) {
      const int flat = i * 1024 + tid * 4;
      const int rr = flat >> 7, cc = flat & 127;
      float4 v;
      if (r0 + rr < nrows) v = *(const float4*)(x + (size_t)(r0 + rr) * DDIM + cc);
      else                 v = make_float4(0.f, 0.f, 0.f, 0.f);
      uint2 pk;
      pk.x = ((unsigned)f2bf(v.y) << 16) | f2bf(v.x);
      pk.y = ((unsigned)f2bf(v.w) << 16) | f2bf(v.z);
      const int byte = (rr * 256 + cc * 2) ^ ((rr & 7) << 4);
      *(uint2*)((char*)xs + byte) = pk;
    }
    __syncthreads();

    f32x4 acc[4][2][2];
#pragma unroll
    for (int rt = 0; rt < 4; ++rt)
#pragma unroll
      for (int m = 0; m < 2; ++m)
#pragma unroll
        for (int ct = 0; ct < 2; ++ct)
          acc[rt][m][ct] = (f32x4){0.f, 0.f, 0.f, 0.f};

#pragma unroll
    for (int ks = 0; ks < 4; ++ks) {
#pragma unroll
      for (int rt = 0; rt < 4; ++rt) {
        const int rr = rt * 16 + col16;
        const int byte = (rr * 256 + (ks * 64 + kgrp * 16)) ^ ((rr & 7) << 4);
        short8 a = *(const short8*)((char*)xs + byte);
#pragma unroll
        for (int m = 0; m < 2; ++m)
#pragma unroll
          for (int ct = 0; ct < 2; ++ct)
            acc[rt][m][ct] = __builtin_amdgcn_mfma_f32_16x16x32_bf16(a, wf[m][ct][ks], acc[rt][m][ct], 0, 0, 0);
      }
    }

#pragma unroll
    for (int rt = 0; rt < 4; ++rt)
#pragma unroll
      for (int ct = 0; ct < 2; ++ct) {
        const int c = wv * 32 + ct * 16 + col16;
#pragma unroll
        for (int i = 0; i < 4; ++i) {
          const int r = r0 + rt * 16 + kgrp * 4 + i;
          if (r < nrows) {
            const float y1 = acc[rt][0][ct][i] + b1c[ct];
            const float y2 = acc[rt][1][ct][i];
            Aout[(size_t)r * DDIM + c] = f2bf(y1 + y2 + b2c[ct]);
            Qout[(size_t)r * DDIM + c] = f2bf(y2);
          }
        }
      }
  }
}

// ---- combined histogram over both edge types (dst rows: user 0..NU-1, item NU..)
__global__ void hist(const int* __restrict__ dst_ui, const float* __restrict__ nrm_ui, int nE_ui,
                     const int* __restrict__ dst_iu, const float* __restrict__ nrm_iu, int nE_iu,
                     int NU, int* __restrict__ deg, float* __restrict__ S) {
  int i = blockIdx.x * blockDim.x + threadIdx.x;
  int stride = gridDim.x * blockDim.x;
  int nTot = nE_ui + nE_iu;
  for (; i < nTot; i += stride) {
    int d; float nm;
    if (i < nE_ui) { d = NU + dst_ui[i]; nm = nrm_ui[i]; }
    else           { d = dst_iu[i - nE_ui]; nm = nrm_iu[i - nE_ui]; }
    atomicAdd(&deg[d], 1);
    atomicAdd(&S[d], nm);
  }
}

__global__ __launch_bounds__(1024) void scan1(const int* __restrict__ deg, int n,
                                              int* __restrict__ exsc, int* __restrict__ bsum) {
  __shared__ int wsum[16];
  const int tid = threadIdx.x;
  const int g = blockIdx.x * 1024 + tid;
  const int lane = tid & 63, wv = tid >> 6;
  int v = (g < n) ? deg[g] : 0;
  int x = v;
#pragma unroll
  for (int off = 1; off < 64; off <<= 1) {
    int y = __shfl_up(x, off);
    if (lane >= off) x += y;
  }
  if (lane == 63) wsum[wv] = x;
  __syncthreads();
  if (wv == 0 && lane < 16) {
    int s = wsum[lane];
#pragma unroll
    for (int off = 1; off < 16; off <<= 1) {
      int y = __shfl_up(s, off);
      if (lane >= off) s += y;
    }
    wsum[lane] = s;
  }
  __syncthreads();
  int woff = (wv == 0) ? 0 : wsum[wv - 1];
  int inc = x + woff;
  if (g < n) exsc[g] = inc - v;
  if (tid == 1023) bsum[blockIdx.x] = inc;
}

__global__ __launch_bounds__(256) void scan2(int* __restrict__ bsum, int nb) {
  __shared__ int tmp[256];
  const int tid = threadIdx.x;
  int v = (tid < nb) ? bsum[tid] : 0;
  int x = v;
  tmp[tid] = v;
  __syncthreads();
#pragma unroll
  for (int off = 1; off < 256; off <<= 1) {
    int y = (tid >= off) ? tmp[tid - off] : 0;
    __syncthreads();
    x += y;
    tmp[tid] = x;
    __syncthreads();
  }
  if (tid < nb) bsum[tid] = x - v;
}

__global__ void scan3(const int* __restrict__ exsc, const int* __restrict__ bsum,
                      int n, int nETot, int* __restrict__ rowptr, int* __restrict__ cursor) {
  int g = blockIdx.x * blockDim.x + threadIdx.x;
  if (g < n) {
    int v = exsc[g] + bsum[g >> 10];
    rowptr[g] = v;
    cursor[g] = v;
  }
  if (g == n) rowptr[n] = nETot;
}

__global__ void fillcsr(const int* __restrict__ src_ui, const int* __restrict__ dst_ui,
                        const float* __restrict__ nrm_ui, int nE_ui,
                        const int* __restrict__ src_iu, const int* __restrict__ dst_iu,
                        const float* __restrict__ nrm_iu, int nE_iu,
                        int NU, int* __restrict__ cursor, int2* __restrict__ pay) {
  int i = blockIdx.x * blockDim.x + threadIdx.x;
  int stride = gridDim.x * blockDim.x;
  int nTot = nE_ui + nE_iu;
  for (; i < nTot; i += stride) {
    int d, s; float nm;
    if (i < nE_ui) { d = NU + dst_ui[i]; s = src_ui[i]; nm = nrm_ui[i]; }
    else { int k = i - nE_ui; d = dst_iu[k]; s = src_iu[k]; nm = nrm_iu[k]; }
    int pos = atomicAdd(&cursor[d], 1);
    int2 p; p.x = s; p.y = __float_as_int(nm);
    pay[pos] = p;
  }
}

// ---- pullfin v2: half-wave (32-lane) rows, 4-deep gather unroll, nt store.
// h[r] = A_self[r] + (S[r]-1)*Q[r] - b2 + sum_e norm_e * A_gather[src_e]; then lrelu+L2norm.
__global__ __launch_bounds__(256) void pullfin(
    const int* __restrict__ rowptr, const int2* __restrict__ pay,
    const unsigned short* __restrict__ Ac,
    const unsigned short* __restrict__ Au, const unsigned short* __restrict__ Ai,
    const unsigned short* __restrict__ Qc, const float* __restrict__ S,
    const float* __restrict__ b2,
    float* __restrict__ out, int NU, int ntot) {
  const int lane = threadIdx.x & 63;
  const int h    = lane & 31;          // lane within half-wave
  const int half = lane >> 5;
  float b2v[4];
#pragma unroll
  for (int j = 0; j < 4; ++j) b2v[j] = b2[h * 4 + j];

  int r = (((blockIdx.x * blockDim.x + threadIdx.x) >> 6) << 1) + half;
  const int rstride = ((gridDim.x * blockDim.x) >> 6) << 1;
  for (; r < ntot; r += rstride) {
    const unsigned short* Ag = (r < NU) ? Ai : Au;
    const int beg = rowptr[r], end = rowptr[r + 1];
    float a0 = 0.f, a1 = 0.f, a2 = 0.f, a3 = 0.f;
    int e = beg;
    for (; e + 3 < end; e += 4) {
      int2 p0 = pay[e], p1 = pay[e + 1], p2 = pay[e + 2], p3 = pay[e + 3];
      uint2 g0 = *(const uint2*)(Ag + (size_t)p0.x * DDIM + h * 4);
      uint2 g1 = *(const uint2*)(Ag + (size_t)p1.x * DDIM + h * 4);
      uint2 g2 = *(const uint2*)(Ag + (size_t)p2.x * DDIM + h * 4);
      uint2 g3 = *(const uint2*)(Ag + (size_t)p3.x * DDIM + h * 4);
      float n0 = __int_as_float(p0.y), n1 = __int_as_float(p1.y);
      float n2 = __int_as_float(p2.y), n3 = __int_as_float(p3.y);
      a0 += n0 * bf2f((unsigned short)(g0.x & 0xffffu));
      a1 += n0 * bf2f((unsigned short)(g0.x >> 16));
      a2 += n0 * bf2f((unsigned short)(g0.y & 0xffffu));
      a3 += n0 * bf2f((unsigned short)(g0.y >> 16));
      a0 += n1 * bf2f((unsigned short)(g1.x & 0xffffu));
      a1 += n1 * bf2f((unsigned short)(g1.x >> 16));
      a2 += n1 * bf2f((unsigned short)(g1.y & 0xffffu));
      a3 += n1 * bf2f((unsigned short)(g1.y >> 16));
      a0 += n2 * bf2f((unsigned short)(g2.x & 0xffffu));
      a1 += n2 * bf2f((unsigned short)(g2.x >> 16));
      a2 += n2 * bf2f((unsigned short)(g2.y & 0xffffu));
      a3 += n2 * bf2f((unsigned short)(g2.y >> 16));
      a0 += n3 * bf2f((unsigned short)(g3.x & 0xffffu));
      a1 += n3 * bf2f((unsigned short)(g3.x >> 16));
      a2 += n3 * bf2f((unsigned short)(g3.y & 0xffffu));
      a3 += n3 * bf2f((unsigned short)(g3.y >> 16));
    }
    for (; e < end; ++e) {
      int2 p0 = pay[e];
      uint2 g0 = *(const uint2*)(Ag + (size_t)p0.x * DDIM + h * 4);
      float n0 = __int_as_float(p0.y);
      a0 += n0 * bf2f((unsigned short)(g0.x & 0xffffu));
      a1 += n0 * bf2f((unsigned short)(g0.x >> 16));
      a2 += n0 * bf2f((unsigned short)(g0.y & 0xffffu));
      a3 += n0 * bf2f((unsigned short)(g0.y >> 16));
    }

    uint2 av = *(const uint2*)(Ac + (size_t)r * DDIM + h * 4);
    uint2 qv = *(const uint2*)(Qc + (size_t)r * DDIM + h * 4);
    const float s1 = S[r] - 1.0f;
    float v0 = bf2f((unsigned short)(av.x & 0xffffu)) + s1 * bf2f((unsigned short)(qv.x & 0xffffu)) - b2v[0] + a0;
    float v1 = bf2f((unsigned short)(av.x >> 16))     + s1 * bf2f((unsigned short)(qv.x >> 16))     - b2v[1] + a1;
    float v2 = bf2f((unsigned short)(av.y & 0xffffu)) + s1 * bf2f((unsigned short)(qv.y & 0xffffu)) - b2v[2] + a2;
    float v3 = bf2f((unsigned short)(av.y >> 16))     + s1 * bf2f((unsigned short)(qv.y >> 16))     - b2v[3] + a3;

    v0 = v0 > 0.f ? v0 : 0.2f * v0;
    v1 = v1 > 0.f ? v1 : 0.2f * v1;
    v2 = v2 > 0.f ? v2 : 0.2f * v2;
    v3 = v3 > 0.f ? v3 : 0.2f * v3;
    float sq = v0 * v0 + v1 * v1 + v2 * v2 + v3 * v3;
#pragma unroll
    for (int off = 16; off; off >>= 1) sq += __shfl_xor(sq, off);  // within 32-lane half
    float sc = 1.0f / fmaxf(sqrtf(sq), 1e-12f);
    f32x4 res;
    res.x = v0 * sc; res.y = v1 * sc; res.z = v2 * sc; res.w = v3 * sc;
    __builtin_nontemporal_store(res, (f32x4*)(out + (size_t)r * DDIM + h * 4));
  }
}

extern "C" void kernel_launch(void* const* d_in, const int* in_sizes, int n_in,
                              void* d_out, int out_size, void* d_ws, size_t ws_size,
                              hipStream_t stream) {
  const float* x_user  = (const float*)d_in[0];
  const float* x_item  = (const float*)d_in[1];
  const float* W1      = (const float*)d_in[2];
  const float* b1      = (const float*)d_in[3];
  const float* W2      = (const float*)d_in[4];
  const float* b2      = (const float*)d_in[5];
  const int*   src_ui  = (const int*)d_in[6];
  const int*   dst_ui  = (const int*)d_in[7];
  const float* norm_ui = (const float*)d_in[8];
  const int*   src_iu  = (const int*)d_in[9];
  const int*   dst_iu  = (const int*)d_in[10];
  const float* norm_iu = (const float*)d_in[11];

  const int NUr   = in_sizes[0] / DDIM;   // 100000
  const int NIr   = in_sizes[1] / DDIM;   // 50000
  const int nE_ui = in_sizes[6];          // 300000
  const int nE_iu = in_sizes[9];
  const int nTot  = NUr + NIr;
  const int nETot = nE_ui + nE_iu;

  float* out = (float*)d_out;             // rows: [h_user (NUr); h_item (NIr)]

  char* ws = (char*)d_ws;
  size_t off = 0;
  auto alloc = [&](size_t bytes) { char* p = ws + off; off += (bytes + 15) & ~(size_t)15; return p; };
  unsigned short* wb  = (unsigned short*)alloc(32768 * 2);
  unsigned short* Ac  = (unsigned short*)alloc((size_t)nTot * DDIM * 2);  // [Au; Ai]
  unsigned short* Qc  = (unsigned short*)alloc((size_t)nTot * DDIM * 2);  // [Qu; Qi]
  float* S            = (float*)alloc((size_t)nTot * 4);
  int*   deg          = (int*)alloc((size_t)nTot * 4);
  int*   exsc         = (int*)alloc((size_t)nTot * 4);
  int*   bsum         = (int*)alloc(256 * 4);
  int*   cursor       = (int*)alloc((size_t)nTot * 4);
  int*   rowptr       = (int*)alloc(((size_t)nTot + 1) * 4);
  int2*  pay          = (int2*)alloc((size_t)nETot * 8);

  unsigned short* Au = Ac;
  unsigned short* Ai = Ac + (size_t)NUr * DDIM;

  (void)hipMemsetAsync(S, 0, (size_t)nTot * 8, stream);

  convW<<<128, 256, 0, stream>>>(W1, W2, wb);
  proj<<<1563, 256, 0, stream>>>(x_user, NUr, wb, b1, b2, Au, Qc);
  proj<<<782, 256, 0, stream>>>(x_item, NIr, wb, b1, b2, Ai, Qc + (size_t)NUr * DDIM);

  const int nb = (nTot + 1023) / 1024;    // 147
  hist<<<2048, 256, 0, stream>>>(dst_ui, norm_ui, nE_ui, dst_iu, norm_iu, nE_iu, NUr, deg, S);
  scan1<<<nb, 1024, 0, stream>>>(deg, nTot, exsc, bsum);
  scan2<<<1, 256, 0, stream>>>(bsum, nb);
  scan3<<<(nTot + 256) / 256, 256, 0, stream>>>(exsc, bsum, nTot, nETot, rowptr, cursor);
  fillcsr<<<2048, 256, 0, stream>>>(src_ui, dst_ui, norm_ui, nE_ui,
                                    src_iu, dst_iu, norm_iu, nE_iu, NUr, cursor, pay);
  pullfin<<<18752, 256, 0, stream>>>(rowptr, pay, Ac, Au, Ai, Qc, S, b2, out, NUr, nTot);
}

// Round 9
// 181.592 us; speedup vs baseline: 3.4815x; 1.2379x over previous
//
#include <hip/hip_runtime.h>
#include <hip/hip_bf16.h>
#include <stdint.h>

typedef __attribute__((ext_vector_type(8))) short short8;
typedef __attribute__((ext_vector_type(4))) float f32x4;

#define DDIM 128

__device__ __forceinline__ unsigned short f2bf(float f) {
  union { float f; unsigned u; } v; v.f = f;
  unsigned u = v.u + 0x7FFFu + ((v.u >> 16) & 1u);  // RNE
  return (unsigned short)(u >> 16);
}
__device__ __forceinline__ float bf2f(unsigned short b) {
  union { unsigned u; float f; } v; v.u = ((unsigned)b) << 16;
  return v.f;
}
__device__ __forceinline__ short8 pack8(float4 a, float4 b) {
  short8 r;
  r[0] = (short)f2bf(a.x); r[1] = (short)f2bf(a.y);
  r[2] = (short)f2bf(a.z); r[3] = (short)f2bf(a.w);
  r[4] = (short)f2bf(b.x); r[5] = (short)f2bf(b.y);
  r[6] = (short)f2bf(b.z); r[7] = (short)f2bf(b.w);
  return r;
}

// ---- proj: one 64-row tile per block; W converted f32->bf16 in prologue
//      (W L2-resident after first blocks). A = bf16(y1+b1+y2+b2), Q = bf16(y2).
__global__ __launch_bounds__(256) void proj(
    const float* __restrict__ x, int nrows, int ntiles,
    const float* __restrict__ W1, const float* __restrict__ W2,
    const float* __restrict__ b1, const float* __restrict__ b2,
    unsigned short* __restrict__ Aout, unsigned short* __restrict__ Qout) {
  __shared__ unsigned short xs[64 * DDIM];
  const int tid   = threadIdx.x;
  const int lane  = tid & 63;
  const int wv    = tid >> 6;
  const int col16 = lane & 15;
  const int kgrp  = lane >> 4;
  const int t = blockIdx.x;
  if (t >= ntiles) return;

  short8 wf[2][2][4];
#pragma unroll
  for (int m = 0; m < 2; ++m) {
    const float* W = m ? W2 : W1;
#pragma unroll
    for (int ct = 0; ct < 2; ++ct) {
      const int c = wv * 32 + ct * 16 + col16;
#pragma unroll
      for (int ks = 0; ks < 4; ++ks) {
        const float* wp = W + (size_t)c * DDIM + ks * 32 + kgrp * 8;
        wf[m][ct][ks] = pack8(*(const float4*)wp, *(const float4*)(wp + 4));
      }
    }
  }
  float b1c[2], b2c[2];
#pragma unroll
  for (int ct = 0; ct < 2; ++ct) {
    const int c = wv * 32 + ct * 16 + col16;
    b1c[ct] = b1[c];
    b2c[ct] = b2[c];
  }

  const int r0 = t * 64;
#pragma unroll
  for (int i = 0; i < 8; ++i) {
    const int flat = i * 1024 + tid * 4;
    const int rr = flat >> 7, cc = flat & 127;
    float4 v;
    if (r0 + rr < nrows) v = *(const float4*)(x + (size_t)(r0 + rr) * DDIM + cc);
    else                 v = make_float4(0.f, 0.f, 0.f, 0.f);
    uint2 pk;
    pk.x = ((unsigned)f2bf(v.y) << 16) | f2bf(v.x);
    pk.y = ((unsigned)f2bf(v.w) << 16) | f2bf(v.z);
    const int byte = (rr * 256 + cc * 2) ^ ((rr & 7) << 4);
    *(uint2*)((char*)xs + byte) = pk;
  }
  __syncthreads();

  f32x4 acc[4][2][2];
#pragma unroll
  for (int rt = 0; rt < 4; ++rt)
#pragma unroll
    for (int m = 0; m < 2; ++m)
#pragma unroll
      for (int ct = 0; ct < 2; ++ct)
        acc[rt][m][ct] = (f32x4){0.f, 0.f, 0.f, 0.f};

#pragma unroll
  for (int ks = 0; ks < 4; ++ks) {
#pragma unroll
    for (int rt = 0; rt < 4; ++rt) {
      const int rr = rt * 16 + col16;
      const int byte = (rr * 256 + (ks * 64 + kgrp * 16)) ^ ((rr & 7) << 4);
      short8 a = *(const short8*)((char*)xs + byte);
#pragma unroll
      for (int m = 0; m < 2; ++m)
#pragma unroll
        for (int ct = 0; ct < 2; ++ct)
          acc[rt][m][ct] = __builtin_amdgcn_mfma_f32_16x16x32_bf16(a, wf[m][ct][ks], acc[rt][m][ct], 0, 0, 0);
    }
  }

#pragma unroll
  for (int rt = 0; rt < 4; ++rt)
#pragma unroll
    for (int ct = 0; ct < 2; ++ct) {
      const int c = wv * 32 + ct * 16 + col16;
#pragma unroll
      for (int i = 0; i < 4; ++i) {
        const int r = r0 + rt * 16 + kgrp * 4 + i;
        if (r < nrows) {
          const float y1 = acc[rt][0][ct][i] + b1c[ct];
          const float y2 = acc[rt][1][ct][i];
          Aout[(size_t)r * DDIM + c] = f2bf(y1 + y2 + b2c[ct]);
          Qout[(size_t)r * DDIM + c] = f2bf(y2);
        }
      }
    }
}

// ---- hist: rank[i] = per-dst arrival index; ONE atomic per edge, no S.
__global__ void hist(const int* __restrict__ dst_ui, int nE_ui,
                     const int* __restrict__ dst_iu, int nE_iu,
                     int NU, int* __restrict__ deg, int* __restrict__ rank) {
  int i = blockIdx.x * blockDim.x + threadIdx.x;
  const int stride = gridDim.x * blockDim.x;
  const int nTot = nE_ui + nE_iu;
  for (; i < nTot; i += stride) {
    const int d = (i < nE_ui) ? (NU + dst_ui[i]) : dst_iu[i - nE_ui];
    rank[i] = atomicAdd(&deg[d], 1);
  }
}

__global__ __launch_bounds__(1024) void scan1(const int* __restrict__ deg, int n,
                                              int* __restrict__ exsc, int* __restrict__ bsum) {
  __shared__ int wsum[16];
  const int tid = threadIdx.x;
  const int g = blockIdx.x * 1024 + tid;
  const int lane = tid & 63, wv = tid >> 6;
  int v = (g < n) ? deg[g] : 0;
  int x = v;
#pragma unroll
  for (int off = 1; off < 64; off <<= 1) {
    int y = __shfl_up(x, off);
    if (lane >= off) x += y;
  }
  if (lane == 63) wsum[wv] = x;
  __syncthreads();
  if (wv == 0 && lane < 16) {
    int s = wsum[lane];
#pragma unroll
    for (int off = 1; off < 16; off <<= 1) {
      int y = __shfl_up(s, off);
      if (lane >= off) s += y;
    }
    wsum[lane] = s;
  }
  __syncthreads();
  int woff = (wv == 0) ? 0 : wsum[wv - 1];
  int inc = x + woff;
  if (g < n) exsc[g] = inc - v;
  if (tid == 1023) bsum[blockIdx.x] = inc;
}

__global__ __launch_bounds__(256) void scan2(int* __restrict__ bsum, int nb) {
  __shared__ int tmp[256];
  const int tid = threadIdx.x;
  int v = (tid < nb) ? bsum[tid] : 0;
  int x = v;
  tmp[tid] = v;
  __syncthreads();
#pragma unroll
  for (int off = 1; off < 256; off <<= 1) {
    int y = (tid >= off) ? tmp[tid - off] : 0;
    __syncthreads();
    x += y;
    tmp[tid] = x;
    __syncthreads();
  }
  if (tid < nb) bsum[tid] = x - v;
}

__global__ void scan3(const int* __restrict__ exsc, const int* __restrict__ bsum,
                      int n, int nETot, int* __restrict__ rowptr) {
  int g = blockIdx.x * blockDim.x + threadIdx.x;
  if (g < n) rowptr[g] = exsc[g] + bsum[g >> 10];
  if (g == n) rowptr[n] = nETot;
}

// ---- fillcsr: ATOMIC-FREE — pos = rowptr[dst] + rank[i]
__global__ void fillcsr(const int* __restrict__ src_ui, const int* __restrict__ dst_ui,
                        const float* __restrict__ nrm_ui, int nE_ui,
                        const int* __restrict__ src_iu, const int* __restrict__ dst_iu,
                        const float* __restrict__ nrm_iu, int nE_iu,
                        int NU, const int* __restrict__ rowptr,
                        const int* __restrict__ rank, int2* __restrict__ pay) {
  int i = blockIdx.x * blockDim.x + threadIdx.x;
  int stride = gridDim.x * blockDim.x;
  int nTot = nE_ui + nE_iu;
  for (; i < nTot; i += stride) {
    int d, s; float nm;
    if (i < nE_ui) { d = NU + dst_ui[i]; s = src_ui[i]; nm = nrm_ui[i]; }
    else { int k = i - nE_ui; d = dst_iu[k]; s = src_iu[k]; nm = nrm_iu[k]; }
    const int pos = rowptr[d] + rank[i];
    int2 p; p.x = s; p.y = __float_as_int(nm);
    pay[pos] = p;
  }
}

// ---- pullfin v3: S computed inline from payload norms.
// h[r] = A_self[r] + (S-1)*Q[r] - b2 + sum_e norm_e * A_gather[src_e]; lrelu+L2norm.
__global__ __launch_bounds__(256) void pullfin(
    const int* __restrict__ rowptr, const int2* __restrict__ pay,
    const unsigned short* __restrict__ Ac,
    const unsigned short* __restrict__ Au, const unsigned short* __restrict__ Ai,
    const unsigned short* __restrict__ Qc,
    const float* __restrict__ b2,
    float* __restrict__ out, int NU, int ntot) {
  const int lane = threadIdx.x & 63;
  const int h    = lane & 31;
  const int half = lane >> 5;
  float b2v[4];
#pragma unroll
  for (int j = 0; j < 4; ++j) b2v[j] = b2[h * 4 + j];

  int r = (((blockIdx.x * blockDim.x + threadIdx.x) >> 6) << 1) + half;
  const int rstride = ((gridDim.x * blockDim.x) >> 6) << 1;
  for (; r < ntot; r += rstride) {
    const unsigned short* Ag = (r < NU) ? Ai : Au;
    const int beg = rowptr[r], end = rowptr[r + 1];
    float a0 = 0.f, a1 = 0.f, a2 = 0.f, a3 = 0.f, sn = 0.f;
    int e = beg;
    for (; e + 3 < end; e += 4) {
      int2 p0 = pay[e], p1 = pay[e + 1], p2 = pay[e + 2], p3 = pay[e + 3];
      uint2 g0 = *(const uint2*)(Ag + (size_t)p0.x * DDIM + h * 4);
      uint2 g1 = *(const uint2*)(Ag + (size_t)p1.x * DDIM + h * 4);
      uint2 g2 = *(const uint2*)(Ag + (size_t)p2.x * DDIM + h * 4);
      uint2 g3 = *(const uint2*)(Ag + (size_t)p3.x * DDIM + h * 4);
      float n0 = __int_as_float(p0.y), n1 = __int_as_float(p1.y);
      float n2 = __int_as_float(p2.y), n3 = __int_as_float(p3.y);
      sn += (n0 + n1) + (n2 + n3);
      a0 += n0 * bf2f((unsigned short)(g0.x & 0xffffu));
      a1 += n0 * bf2f((unsigned short)(g0.x >> 16));
      a2 += n0 * bf2f((unsigned short)(g0.y & 0xffffu));
      a3 += n0 * bf2f((unsigned short)(g0.y >> 16));
      a0 += n1 * bf2f((unsigned short)(g1.x & 0xffffu));
      a1 += n1 * bf2f((unsigned short)(g1.x >> 16));
      a2 += n1 * bf2f((unsigned short)(g1.y & 0xffffu));
      a3 += n1 * bf2f((unsigned short)(g1.y >> 16));
      a0 += n2 * bf2f((unsigned short)(g2.x & 0xffffu));
      a1 += n2 * bf2f((unsigned short)(g2.x >> 16));
      a2 += n2 * bf2f((unsigned short)(g2.y & 0xffffu));
      a3 += n2 * bf2f((unsigned short)(g2.y >> 16));
      a0 += n3 * bf2f((unsigned short)(g3.x & 0xffffu));
      a1 += n3 * bf2f((unsigned short)(g3.x >> 16));
      a2 += n3 * bf2f((unsigned short)(g3.y & 0xffffu));
      a3 += n3 * bf2f((unsigned short)(g3.y >> 16));
    }
    for (; e < end; ++e) {
      int2 p0 = pay[e];
      uint2 g0 = *(const uint2*)(Ag + (size_t)p0.x * DDIM + h * 4);
      float n0 = __int_as_float(p0.y);
      sn += n0;
      a0 += n0 * bf2f((unsigned short)(g0.x & 0xffffu));
      a1 += n0 * bf2f((unsigned short)(g0.x >> 16));
      a2 += n0 * bf2f((unsigned short)(g0.y & 0xffffu));
      a3 += n0 * bf2f((unsigned short)(g0.y >> 16));
    }

    uint2 av = *(const uint2*)(Ac + (size_t)r * DDIM + h * 4);
    uint2 qv = *(const uint2*)(Qc + (size_t)r * DDIM + h * 4);
    const float s1 = sn - 1.0f;
    float v0 = bf2f((unsigned short)(av.x & 0xffffu)) + s1 * bf2f((unsigned short)(qv.x & 0xffffu)) - b2v[0] + a0;
    float v1 = bf2f((unsigned short)(av.x >> 16))     + s1 * bf2f((unsigned short)(qv.x >> 16))     - b2v[1] + a1;
    float v2 = bf2f((unsigned short)(av.y & 0xffffu)) + s1 * bf2f((unsigned short)(qv.y & 0xffffu)) - b2v[2] + a2;
    float v3 = bf2f((unsigned short)(av.y >> 16))     + s1 * bf2f((unsigned short)(qv.y >> 16))     - b2v[3] + a3;

    v0 = v0 > 0.f ? v0 : 0.2f * v0;
    v1 = v1 > 0.f ? v1 : 0.2f * v1;
    v2 = v2 > 0.f ? v2 : 0.2f * v2;
    v3 = v3 > 0.f ? v3 : 0.2f * v3;
    float sq = v0 * v0 + v1 * v1 + v2 * v2 + v3 * v3;
#pragma unroll
    for (int off = 16; off; off >>= 1) sq += __shfl_xor(sq, off);
    float sc = 1.0f / fmaxf(sqrtf(sq), 1e-12f);
    f32x4 res;
    res.x = v0 * sc; res.y = v1 * sc; res.z = v2 * sc; res.w = v3 * sc;
    __builtin_nontemporal_store(res, (f32x4*)(out + (size_t)r * DDIM + h * 4));
  }
}

extern "C" void kernel_launch(void* const* d_in, const int* in_sizes, int n_in,
                              void* d_out, int out_size, void* d_ws, size_t ws_size,
                              hipStream_t stream) {
  const float* x_user  = (const float*)d_in[0];
  const float* x_item  = (const float*)d_in[1];
  const float* W1      = (const float*)d_in[2];
  const float* b1      = (const float*)d_in[3];
  const float* W2      = (const float*)d_in[4];
  const float* b2      = (const float*)d_in[5];
  const int*   src_ui  = (const int*)d_in[6];
  const int*   dst_ui  = (const int*)d_in[7];
  const float* norm_ui = (const float*)d_in[8];
  const int*   src_iu  = (const int*)d_in[9];
  const int*   dst_iu  = (const int*)d_in[10];
  const float* norm_iu = (const float*)d_in[11];

  const int NUr   = in_sizes[0] / DDIM;   // 100000
  const int NIr   = in_sizes[1] / DDIM;   // 50000
  const int nE_ui = in_sizes[6];          // 300000
  const int nE_iu = in_sizes[9];
  const int nTot  = NUr + NIr;
  const int nETot = nE_ui + nE_iu;

  float* out = (float*)d_out;             // rows: [h_user (NUr); h_item (NIr)]

  char* ws = (char*)d_ws;
  size_t off = 0;
  auto alloc = [&](size_t bytes) { char* p = ws + off; off += (bytes + 15) & ~(size_t)15; return p; };
  unsigned short* Ac  = (unsigned short*)alloc((size_t)nTot * DDIM * 2);  // [Au; Ai]
  unsigned short* Qc  = (unsigned short*)alloc((size_t)nTot * DDIM * 2);  // [Qu; Qi]
  int*   deg          = (int*)alloc((size_t)nTot * 4);
  int*   exsc         = (int*)alloc((size_t)nTot * 4);
  int*   bsum         = (int*)alloc(256 * 4);
  int*   rowptr       = (int*)alloc(((size_t)nTot + 1) * 4);
  int*   rank         = (int*)alloc((size_t)nETot * 4);
  int2*  pay          = (int2*)alloc((size_t)nETot * 8);

  unsigned short* Au = Ac;
  unsigned short* Ai = Ac + (size_t)NUr * DDIM;
  unsigned short* Qu = Qc;
  unsigned short* Qi = Qc + (size_t)NUr * DDIM;

  (void)hipMemsetAsync(deg, 0, (size_t)nTot * 4, stream);

  const int gU = (NUr + 63) / 64;         // 1563
  const int gI = (NIr + 63) / 64;         // 782

  proj<<<gU, 256, 0, stream>>>(x_user, NUr, gU, W1, W2, b1, b2, Au, Qu);
  proj<<<gI, 256, 0, stream>>>(x_item, NIr, gI, W1, W2, b1, b2, Ai, Qi);
  hist<<<4096, 256, 0, stream>>>(dst_ui, nE_ui, dst_iu, nE_iu, NUr, deg, rank);

  const int nb = (nTot + 1023) / 1024;    // 147
  scan1<<<nb, 1024, 0, stream>>>(deg, nTot, exsc, bsum);
  scan2<<<1, 256, 0, stream>>>(bsum, nb);
  scan3<<<(nTot + 256) / 256, 256, 0, stream>>>(exsc, bsum, nTot, nETot, rowptr);
  fillcsr<<<2048, 256, 0, stream>>>(src_ui, dst_ui, norm_ui, nE_ui,
                                    src_iu, dst_iu, norm_iu, nE_iu, NUr, rowptr, rank, pay);
  pullfin<<<18752, 256, 0, stream>>>(rowptr, pay, Ac, Au, Ai, Qc, b2, out, NUr, nTot);
}

// Round 10
// 147.555 us; speedup vs baseline: 4.2846x; 1.2307x over previous
//
#include <hip/hip_runtime.h>
#include <hip/hip_bf16.h>
#include <stdint.h>

typedef __attribute__((ext_vector_type(8))) short short8;
typedef __attribute__((ext_vector_type(4))) float f32x4;

#define DDIM 128

__device__ __forceinline__ unsigned short f2bf(float f) {
  union { float f; unsigned u; } v; v.f = f;
  unsigned u = v.u + 0x7FFFu + ((v.u >> 16) & 1u);  // RNE
  return (unsigned short)(u >> 16);
}
__device__ __forceinline__ float bf2f(unsigned short b) {
  union { unsigned u; float f; } v; v.u = ((unsigned)b) << 16;
  return v.f;
}

// ---- weights fp32 -> bf16 staging: wb = [W1 rows; W2 rows] = [256][128]
__global__ void convW(const float* __restrict__ W1, const float* __restrict__ W2,
                      unsigned short* __restrict__ wb) {
  int i = blockIdx.x * blockDim.x + threadIdx.x;
  if (i < 16384)      wb[i] = f2bf(W1[i]);
  else if (i < 32768) wb[i] = f2bf(W2[i - 16384]);
}

// ---- proj v4: persistent (grid = 4 blocks/CU), merged user+item tile space,
//      W fragments loaded once per block from bf16 wb (L2-resident).
//      A = bf16(y1+b1+y2+b2), Q = bf16(y2). P reconstructed in pullfin.
__global__ __launch_bounds__(256) void proj(
    const float* __restrict__ xu, int NUr, int gU,
    const float* __restrict__ xi, int NIr, int nTiles,
    const unsigned short* __restrict__ wb,
    const float* __restrict__ b1, const float* __restrict__ b2,
    unsigned short* __restrict__ Au, unsigned short* __restrict__ Qu,
    unsigned short* __restrict__ Ai, unsigned short* __restrict__ Qi) {
  __shared__ unsigned short xs[64 * DDIM];   // 16 KB, XOR-swizzled
  const int tid   = threadIdx.x;
  const int lane  = tid & 63;
  const int wv    = tid >> 6;
  const int col16 = lane & 15;
  const int kgrp  = lane >> 4;

  // one-time per block: W fragments from wb
  short8 wf[2][2][4];
#pragma unroll
  for (int m = 0; m < 2; ++m)
#pragma unroll
    for (int ct = 0; ct < 2; ++ct) {
      const int c = m * 128 + wv * 32 + ct * 16 + col16;
#pragma unroll
      for (int ks = 0; ks < 4; ++ks)
        wf[m][ct][ks] = *(const short8*)(wb + (size_t)c * DDIM + ks * 32 + kgrp * 8);
    }
  float b1c[2], b2c[2];
#pragma unroll
  for (int ct = 0; ct < 2; ++ct) {
    const int c = wv * 32 + ct * 16 + col16;
    b1c[ct] = b1[c];
    b2c[ct] = b2[c];
  }

  for (int t = blockIdx.x; t < nTiles; t += gridDim.x) {
    const bool isU = (t < gU);
    const float* __restrict__ x = isU ? xu : xi;
    const int nrows = isU ? NUr : NIr;
    const int tt    = isU ? t : (t - gU);
    unsigned short* __restrict__ Aout = isU ? Au : Ai;
    unsigned short* __restrict__ Qout = isU ? Qu : Qi;
    const int r0 = tt * 64;

    // ---- stage 64x128 f32 -> bf16 LDS, coalesced
#pragma unroll
    for (int i = 0; i < 8; ++i) {
      const int flat = i * 1024 + tid * 4;
      const int rr = flat >> 7, cc = flat & 127;
      float4 v;
      if (r0 + rr < nrows) v = *(const float4*)(x + (size_t)(r0 + rr) * DDIM + cc);
      else                 v = make_float4(0.f, 0.f, 0.f, 0.f);
      uint2 pk;
      pk.x = ((unsigned)f2bf(v.y) << 16) | f2bf(v.x);
      pk.y = ((unsigned)f2bf(v.w) << 16) | f2bf(v.z);
      const int byte = (rr * 256 + cc * 2) ^ ((rr & 7) << 4);
      *(uint2*)((char*)xs + byte) = pk;
    }
    __syncthreads();

    // ---- MFMA
    f32x4 acc[4][2][2];
#pragma unroll
    for (int rt = 0; rt < 4; ++rt)
#pragma unroll
      for (int m = 0; m < 2; ++m)
#pragma unroll
        for (int ct = 0; ct < 2; ++ct)
          acc[rt][m][ct] = (f32x4){0.f, 0.f, 0.f, 0.f};

#pragma unroll
    for (int ks = 0; ks < 4; ++ks) {
#pragma unroll
      for (int rt = 0; rt < 4; ++rt) {
        const int rr = rt * 16 + col16;
        const int byte = (rr * 256 + (ks * 64 + kgrp * 16)) ^ ((rr & 7) << 4);
        short8 a = *(const short8*)((char*)xs + byte);
#pragma unroll
        for (int m = 0; m < 2; ++m)
#pragma unroll
          for (int ct = 0; ct < 2; ++ct)
            acc[rt][m][ct] = __builtin_amdgcn_mfma_f32_16x16x32_bf16(a, wf[m][ct][ks], acc[rt][m][ct], 0, 0, 0);
      }
    }

    // ---- epilogue
#pragma unroll
    for (int rt = 0; rt < 4; ++rt)
#pragma unroll
      for (int ct = 0; ct < 2; ++ct) {
        const int c = wv * 32 + ct * 16 + col16;
#pragma unroll
        for (int i = 0; i < 4; ++i) {
          const int r = r0 + rt * 16 + kgrp * 4 + i;
          if (r < nrows) {
            const float y1 = acc[rt][0][ct][i] + b1c[ct];
            const float y2 = acc[rt][1][ct][i];
            Aout[(size_t)r * DDIM + c] = f2bf(y1 + y2 + b2c[ct]);
            Qout[(size_t)r * DDIM + c] = f2bf(y2);
          }
        }
      }
    __syncthreads();  // protect xs before next tile's stage
  }
}

// ---- hist: rank[i] = per-dst arrival index; ONE atomic per edge.
__global__ void hist(const int* __restrict__ dst_ui, int nE_ui,
                     const int* __restrict__ dst_iu, int nE_iu,
                     int NU, int* __restrict__ deg, int* __restrict__ rank) {
  int i = blockIdx.x * blockDim.x + threadIdx.x;
  const int stride = gridDim.x * blockDim.x;
  const int nTot = nE_ui + nE_iu;
  for (; i < nTot; i += stride) {
    const int d = (i < nE_ui) ? (NU + dst_ui[i]) : dst_iu[i - nE_ui];
    rank[i] = atomicAdd(&deg[d], 1);
  }
}

__global__ __launch_bounds__(1024) void scan1(const int* __restrict__ deg, int n,
                                              int* __restrict__ exsc, int* __restrict__ bsum) {
  __shared__ int wsum[16];
  const int tid = threadIdx.x;
  const int g = blockIdx.x * 1024 + tid;
  const int lane = tid & 63, wv = tid >> 6;
  int v = (g < n) ? deg[g] : 0;
  int x = v;
#pragma unroll
  for (int off = 1; off < 64; off <<= 1) {
    int y = __shfl_up(x, off);
    if (lane >= off) x += y;
  }
  if (lane == 63) wsum[wv] = x;
  __syncthreads();
  if (wv == 0 && lane < 16) {
    int s = wsum[lane];
#pragma unroll
    for (int off = 1; off < 16; off <<= 1) {
      int y = __shfl_up(s, off);
      if (lane >= off) s += y;
    }
    wsum[lane] = s;
  }
  __syncthreads();
  int woff = (wv == 0) ? 0 : wsum[wv - 1];
  int inc = x + woff;
  if (g < n) exsc[g] = inc - v;
  if (tid == 1023) bsum[blockIdx.x] = inc;
}

__global__ __launch_bounds__(256) void scan2(int* __restrict__ bsum, int nb) {
  __shared__ int tmp[256];
  const int tid = threadIdx.x;
  int v = (tid < nb) ? bsum[tid] : 0;
  int x = v;
  tmp[tid] = v;
  __syncthreads();
#pragma unroll
  for (int off = 1; off < 256; off <<= 1) {
    int y = (tid >= off) ? tmp[tid - off] : 0;
    __syncthreads();
    x += y;
    tmp[tid] = x;
    __syncthreads();
  }
  if (tid < nb) bsum[tid] = x - v;
}

__global__ void scan3(const int* __restrict__ exsc, const int* __restrict__ bsum,
                      int n, int nETot, int* __restrict__ rowptr) {
  int g = blockIdx.x * blockDim.x + threadIdx.x;
  if (g < n) rowptr[g] = exsc[g] + bsum[g >> 10];
  if (g == n) rowptr[n] = nETot;
}

// ---- fillcsr: ATOMIC-FREE — pos = rowptr[dst] + rank[i]
__global__ void fillcsr(const int* __restrict__ src_ui, const int* __restrict__ dst_ui,
                        const float* __restrict__ nrm_ui, int nE_ui,
                        const int* __restrict__ src_iu, const int* __restrict__ dst_iu,
                        const float* __restrict__ nrm_iu, int nE_iu,
                        int NU, const int* __restrict__ rowptr,
                        const int* __restrict__ rank, int2* __restrict__ pay) {
  int i = blockIdx.x * blockDim.x + threadIdx.x;
  int stride = gridDim.x * blockDim.x;
  int nTot = nE_ui + nE_iu;
  for (; i < nTot; i += stride) {
    int d, s; float nm;
    if (i < nE_ui) { d = NU + dst_ui[i]; s = src_ui[i]; nm = nrm_ui[i]; }
    else { int k = i - nE_ui; d = dst_iu[k]; s = src_iu[k]; nm = nrm_iu[k]; }
    const int pos = rowptr[d] + rank[i];
    int2 p; p.x = s; p.y = __float_as_int(nm);
    pay[pos] = p;
  }
}

// ---- pullfin v3: S computed inline from payload norms.
// h[r] = A_self[r] + (S-1)*Q[r] - b2 + sum_e norm_e * A_gather[src_e]; lrelu+L2norm.
__global__ __launch_bounds__(256) void pullfin(
    const int* __restrict__ rowptr, const int2* __restrict__ pay,
    const unsigned short* __restrict__ Ac,
    const unsigned short* __restrict__ Au, const unsigned short* __restrict__ Ai,
    const unsigned short* __restrict__ Qc,
    const float* __restrict__ b2,
    float* __restrict__ out, int NU, int ntot) {
  const int lane = threadIdx.x & 63;
  const int h    = lane & 31;
  const int half = lane >> 5;
  float b2v[4];
#pragma unroll
  for (int j = 0; j < 4; ++j) b2v[j] = b2[h * 4 + j];

  int r = (((blockIdx.x * blockDim.x + threadIdx.x) >> 6) << 1) + half;
  const int rstride = ((gridDim.x * blockDim.x) >> 6) << 1;
  for (; r < ntot; r += rstride) {
    const unsigned short* Ag = (r < NU) ? Ai : Au;
    const int beg = rowptr[r], end = rowptr[r + 1];
    float a0 = 0.f, a1 = 0.f, a2 = 0.f, a3 = 0.f, sn = 0.f;
    int e = beg;
    for (; e + 3 < end; e += 4) {
      int2 p0 = pay[e], p1 = pay[e + 1], p2 = pay[e + 2], p3 = pay[e + 3];
      uint2 g0 = *(const uint2*)(Ag + (size_t)p0.x * DDIM + h * 4);
      uint2 g1 = *(const uint2*)(Ag + (size_t)p1.x * DDIM + h * 4);
      uint2 g2 = *(const uint2*)(Ag + (size_t)p2.x * DDIM + h * 4);
      uint2 g3 = *(const uint2*)(Ag + (size_t)p3.x * DDIM + h * 4);
      float n0 = __int_as_float(p0.y), n1 = __int_as_float(p1.y);
      float n2 = __int_as_float(p2.y), n3 = __int_as_float(p3.y);
      sn += (n0 + n1) + (n2 + n3);
      a0 += n0 * bf2f((unsigned short)(g0.x & 0xffffu));
      a1 += n0 * bf2f((unsigned short)(g0.x >> 16));
      a2 += n0 * bf2f((unsigned short)(g0.y & 0xffffu));
      a3 += n0 * bf2f((unsigned short)(g0.y >> 16));
      a0 += n1 * bf2f((unsigned short)(g1.x & 0xffffu));
      a1 += n1 * bf2f((unsigned short)(g1.x >> 16));
      a2 += n1 * bf2f((unsigned short)(g1.y & 0xffffu));
      a3 += n1 * bf2f((unsigned short)(g1.y >> 16));
      a0 += n2 * bf2f((unsigned short)(g2.x & 0xffffu));
      a1 += n2 * bf2f((unsigned short)(g2.x >> 16));
      a2 += n2 * bf2f((unsigned short)(g2.y & 0xffffu));
      a3 += n2 * bf2f((unsigned short)(g2.y >> 16));
      a0 += n3 * bf2f((unsigned short)(g3.x & 0xffffu));
      a1 += n3 * bf2f((unsigned short)(g3.x >> 16));
      a2 += n3 * bf2f((unsigned short)(g3.y & 0xffffu));
      a3 += n3 * bf2f((unsigned short)(g3.y >> 16));
    }
    for (; e < end; ++e) {
      int2 p0 = pay[e];
      uint2 g0 = *(const uint2*)(Ag + (size_t)p0.x * DDIM + h * 4);
      float n0 = __int_as_float(p0.y);
      sn += n0;
      a0 += n0 * bf2f((unsigned short)(g0.x & 0xffffu));
      a1 += n0 * bf2f((unsigned short)(g0.x >> 16));
      a2 += n0 * bf2f((unsigned short)(g0.y & 0xffffu));
      a3 += n0 * bf2f((unsigned short)(g0.y >> 16));
    }

    uint2 av = *(const uint2*)(Ac + (size_t)r * DDIM + h * 4);
    uint2 qv = *(const uint2*)(Qc + (size_t)r * DDIM + h * 4);
    const float s1 = sn - 1.0f;
    float v0 = bf2f((unsigned short)(av.x & 0xffffu)) + s1 * bf2f((unsigned short)(qv.x & 0xffffu)) - b2v[0] + a0;
    float v1 = bf2f((unsigned short)(av.x >> 16))     + s1 * bf2f((unsigned short)(qv.x >> 16))     - b2v[1] + a1;
    float v2 = bf2f((unsigned short)(av.y & 0xffffu)) + s1 * bf2f((unsigned short)(qv.y & 0xffffu)) - b2v[2] + a2;
    float v3 = bf2f((unsigned short)(av.y >> 16))     + s1 * bf2f((unsigned short)(qv.y >> 16))     - b2v[3] + a3;

    v0 = v0 > 0.f ? v0 : 0.2f * v0;
    v1 = v1 > 0.f ? v1 : 0.2f * v1;
    v2 = v2 > 0.f ? v2 : 0.2f * v2;
    v3 = v3 > 0.f ? v3 : 0.2f * v3;
    float sq = v0 * v0 + v1 * v1 + v2 * v2 + v3 * v3;
#pragma unroll
    for (int off = 16; off; off >>= 1) sq += __shfl_xor(sq, off);
    float sc = 1.0f / fmaxf(sqrtf(sq), 1e-12f);
    f32x4 res;
    res.x = v0 * sc; res.y = v1 * sc; res.z = v2 * sc; res.w = v3 * sc;
    __builtin_nontemporal_store(res, (f32x4*)(out + (size_t)r * DDIM + h * 4));
  }
}

extern "C" void kernel_launch(void* const* d_in, const int* in_sizes, int n_in,
                              void* d_out, int out_size, void* d_ws, size_t ws_size,
                              hipStream_t stream) {
  const float* x_user  = (const float*)d_in[0];
  const float* x_item  = (const float*)d_in[1];
  const float* W1      = (const float*)d_in[2];
  const float* b1      = (const float*)d_in[3];
  const float* W2      = (const float*)d_in[4];
  const float* b2      = (const float*)d_in[5];
  const int*   src_ui  = (const int*)d_in[6];
  const int*   dst_ui  = (const int*)d_in[7];
  const float* norm_ui = (const float*)d_in[8];
  const int*   src_iu  = (const int*)d_in[9];
  const int*   dst_iu  = (const int*)d_in[10];
  const float* norm_iu = (const float*)d_in[11];

  const int NUr   = in_sizes[0] / DDIM;   // 100000
  const int NIr   = in_sizes[1] / DDIM;   // 50000
  const int nE_ui = in_sizes[6];          // 300000
  const int nE_iu = in_sizes[9];
  const int nTot  = NUr + NIr;
  const int nETot = nE_ui + nE_iu;

  float* out = (float*)d_out;             // rows: [h_user (NUr); h_item (NIr)]

  char* ws = (char*)d_ws;
  size_t off = 0;
  auto alloc = [&](size_t bytes) { char* p = ws + off; off += (bytes + 15) & ~(size_t)15; return p; };
  unsigned short* wb  = (unsigned short*)alloc(32768 * 2);
  unsigned short* Ac  = (unsigned short*)alloc((size_t)nTot * DDIM * 2);  // [Au; Ai]
  unsigned short* Qc  = (unsigned short*)alloc((size_t)nTot * DDIM * 2);  // [Qu; Qi]
  int*   deg          = (int*)alloc((size_t)nTot * 4);
  int*   exsc         = (int*)alloc((size_t)nTot * 4);
  int*   bsum         = (int*)alloc(256 * 4);
  int*   rowptr       = (int*)alloc(((size_t)nTot + 1) * 4);
  int*   rank         = (int*)alloc((size_t)nETot * 4);
  int2*  pay          = (int2*)alloc((size_t)nETot * 8);

  unsigned short* Au = Ac;
  unsigned short* Ai = Ac + (size_t)NUr * DDIM;
  unsigned short* Qu = Qc;
  unsigned short* Qi = Qc + (size_t)NUr * DDIM;

  (void)hipMemsetAsync(deg, 0, (size_t)nTot * 4, stream);

  const int gU = (NUr + 63) / 64;         // 1563
  const int gI = (NIr + 63) / 64;         // 782
  const int nTiles = gU + gI;             // 2345

  convW<<<128, 256, 0, stream>>>(W1, W2, wb);
  proj<<<1024, 256, 0, stream>>>(x_user, NUr, gU, x_item, NIr, nTiles,
                                 wb, b1, b2, Au, Qu, Ai, Qi);
  hist<<<4096, 256, 0, stream>>>(dst_ui, nE_ui, dst_iu, nE_iu, NUr, deg, rank);

  const int nb = (nTot + 1023) / 1024;    // 147
  scan1<<<nb, 1024, 0, stream>>>(deg, nTot, exsc, bsum);
  scan2<<<1, 256, 0, stream>>>(bsum, nb);
  scan3<<<(nTot + 256) / 256, 256, 0, stream>>>(exsc, bsum, nTot, nETot, rowptr);
  fillcsr<<<2048, 256, 0, stream>>>(src_ui, dst_ui, norm_ui, nE_ui,
                                    src_iu, dst_iu, norm_iu, nE_iu, NUr, rowptr, rank, pay);
  pullfin<<<18752, 256, 0, stream>>>(rowptr, pay, Ac, Au, Ai, Qc, b2, out, NUr, nTot);
}